// Round 8
// baseline (411.933 us; speedup 1.0000x reference)
//
#include <hip/hip_runtime.h>
#include <cstdint>

// Problem constants
#define TT 512   // KVLEN
#define CC 512   // C
#define HH 8     // heads
#define NN 64    // head dim
#define BQ 32    // BATCH*QLEN
#define NB 4     // BATCH
#define TG 128   // TT/4 packed groups

__device__ __forceinline__ float sigm(float x){ return 1.f/(1.f+__expf(-x)); }

__device__ __forceinline__ float wsum(float x){
  #pragma unroll
  for (int o=32;o;o>>=1) x += __shfl_xor(x, o, 64);
  return x;
}

// ---------------------------------------------------------------------------
// Batched wave64 row-sum, VALU-only: DPP row_ror tree + permlane16/32 swap.
// ---------------------------------------------------------------------------
template<int NR>
__device__ __forceinline__ void rowsum64_batch(float* x){
  #pragma unroll
  for (int i=0;i<NR;i++)
    x[i] += __int_as_float(__builtin_amdgcn_mov_dpp(__float_as_int(x[i]), 0x121, 0xf, 0xf, true));
  #pragma unroll
  for (int i=0;i<NR;i++)
    x[i] += __int_as_float(__builtin_amdgcn_mov_dpp(__float_as_int(x[i]), 0x122, 0xf, 0xf, true));
  #pragma unroll
  for (int i=0;i<NR;i++)
    x[i] += __int_as_float(__builtin_amdgcn_mov_dpp(__float_as_int(x[i]), 0x124, 0xf, 0xf, true));
  #pragma unroll
  for (int i=0;i<NR;i++)
    x[i] += __int_as_float(__builtin_amdgcn_mov_dpp(__float_as_int(x[i]), 0x128, 0xf, 0xf, true));
  float y[NR];
  #pragma unroll
  for (int i=0;i<NR;i++) asm("v_mov_b32 %0, %1" : "=v"(y[i]) : "v"(x[i]));
  #pragma unroll
  for (int i=0;i<NR;i++) asm("v_permlane16_swap_b32 %0, %1" : "+v"(x[i]), "+v"(y[i]));
  #pragma unroll
  for (int i=0;i<NR;i++) x[i] += y[i];
  #pragma unroll
  for (int i=0;i<NR;i++) asm("v_mov_b32 %0, %1" : "=v"(y[i]) : "v"(x[i]));
  #pragma unroll
  for (int i=0;i<NR;i++) asm("v_permlane32_swap_b32 %0, %1" : "+v"(x[i]), "+v"(y[i]));
  #pragma unroll
  for (int i=0;i<NR;i++) x[i] += y[i];
}

// ---------------------------------------------------------------------------
// k_prep: per-bq small dots (32 blocks): Qw[bq,32], Qa[bq,32], gh[bq,96],
// and xr row -> workspace.
// ---------------------------------------------------------------------------
__global__ __launch_bounds__(256) void k_prep(
  const float* __restrict__ q, const float* __restrict__ kv,
  const float* __restrict__ x_r, const float* __restrict__ x_w,
  const float* __restrict__ x_a, const float* __restrict__ x_g,
  const float* __restrict__ w1, const float* __restrict__ a1,
  const float* __restrict__ g1,
  float* __restrict__ Qw, float* __restrict__ Qa,
  float* __restrict__ ghw, float* __restrict__ xrw)
{
  int bq = blockIdx.x, b = bq >> 3, tid = threadIdx.x;
  int wave = tid >> 6, lane = tid & 63;
  __shared__ float qxw[CC], qxa[CC], sxg[CC];
  for (int c = tid; c < CC; c += 256){
    float qv = q[bq*CC + c];
    float kl = kv[((size_t)b*TT + (TT-1))*CC + c];
    xrw[bq*CC + c] = kl + (qv - kl)*x_r[c];
    sxg[c] = kl + (qv - kl)*x_g[c];
    qxw[c] = qv*x_w[c];
    qxa[c] = qv*x_a[c];
  }
  __syncthreads();
  for (int dot = wave; dot < 160; dot += 4){
    const float* buf; const float* W; int ld, dd;
    if (dot < 32)      { buf = qxw; W = w1; ld = 32; dd = dot; }
    else if (dot < 64) { buf = qxa; W = a1; ld = 32; dd = dot-32; }
    else               { buf = sxg; W = g1; ld = 96; dd = dot-64; }
    float s = 0.f;
    #pragma unroll
    for (int m = 0; m < 8; m++){
      int c = m*64 + lane;
      s = fmaf(buf[c], W[c*ld + dd], s);
    }
    s = wsum(s);
    if (lane == 0){
      if (dot < 32)      Qw[bq*32 + dd] = s;
      else if (dot < 64) Qa[bq*32 + dd] = s;
      else               ghw[bq*96 + dd] = sigm(s);
    }
  }
}

// ---------------------------------------------------------------------------
// k_rg: rrow[bq,co] = xr[bq,:]@Wr[:,co], grow[bq,co] = gh[bq,:]@g2[:,co]
// ---------------------------------------------------------------------------
__global__ __launch_bounds__(256) void k_rg(
  const float* __restrict__ xrw, const float* __restrict__ ghw,
  const float* __restrict__ Wr, const float* __restrict__ g2,
  float* __restrict__ rrow, float* __restrict__ grow)
{
  int bq = blockIdx.y; int co0 = blockIdx.x*64;
  int tid = threadIdx.x, tx = tid & 63, ty = tid >> 6;
  __shared__ float sxr[CC];
  __shared__ float sgh[96];
  __shared__ float red[4][64];
  sxr[tid]     = xrw[bq*CC + tid];
  sxr[tid+256] = xrw[bq*CC + tid + 256];
  if (tid < 96) sgh[tid] = ghw[bq*96 + tid];
  __syncthreads();
  float p = 0.f;
  for (int i = 0; i < 128; i++){
    int c = ty*128 + i;
    p = fmaf(sxr[c], Wr[(size_t)c*CC + co0 + tx], p);
  }
  red[ty][tx] = p;
  float pg = 0.f;
  for (int d = ty*24; d < ty*24 + 24; d++)
    pg = fmaf(sgh[d], g2[(size_t)d*CC + co0 + tx], pg);
  __syncthreads();
  if (ty == 0)
    rrow[bq*CC + co0 + tx] = (red[0][tx]+red[1][tx])+(red[2][tx]+red[3][tx]);
  __syncthreads();
  red[ty][tx] = pg;
  __syncthreads();
  if (ty == 0)
    grow[bq*CC + co0 + tx] = (red[0][tx]+red[1][tx])+(red[2][tx]+red[3][tx]);
}

// ---------------------------------------------------------------------------
// k_pgemm: three [2048x512]@[512x32] products (Pw, Pa, HV), tiled.
// R8: token-shift FUSED into A staging (xv intermediate deleted): for mat2
// A = xv = kv + (shift-kv)*x_v computed on the fly; mat0/1 read kv as before
// (xm=0 makes the lerp a no-op).
// ---------------------------------------------------------------------------
__global__ __launch_bounds__(256) void k_pgemm(
  const float* __restrict__ kv,
  const float* __restrict__ x_w, const float* __restrict__ x_a,
  const float* __restrict__ x_v,
  const float* __restrict__ w1, const float* __restrict__ a1,
  const float* __restrict__ v1,
  float* __restrict__ Pw, float* __restrict__ Pa, float* __restrict__ HV)
{
  int mat = blockIdx.y;
  int r0 = blockIdx.x * 64;
  const float* B = (mat == 0) ? w1 : (mat == 1) ? a1 : v1;
  float* O       = (mat == 0) ? Pw : (mat == 1) ? Pa : HV;
  int tid = threadIdx.x;
  __shared__ float As[32][65];
  __shared__ float Bs[32][32];
  __shared__ float scl[CC];
  __shared__ float xm[CC];
  for (int c = tid; c < CC; c += 256){
    scl[c] = (mat == 0) ? (1.f - x_w[c]) : (mat == 1) ? (1.f - x_a[c]) : 1.f;
    xm[c]  = (mat == 2) ? x_v[c] : 0.f;
  }
  __syncthreads();
  int tx = tid & 31, ty = tid >> 5;
  float acc[8];
  #pragma unroll
  for (int i = 0; i < 8; i++) acc[i] = 0.f;
  for (int k0 = 0; k0 < 512; k0 += 32){
    #pragma unroll
    for (int p = 0; p < 8; p++){
      int e = tid + p*256;
      int kk2 = e & 31, r = e >> 5;
      int m = r0 + r, col = k0 + kk2;
      float cur = kv[(size_t)m*512 + col];
      int t = m & (TT-1);
      float sh = t ? kv[(size_t)(m-1)*512 + col] : 0.f;
      As[kk2][r] = fmaf(sh - cur, xm[col], cur) * scl[col];
    }
    #pragma unroll
    for (int p = 0; p < 4; p++){
      int e = tid + p*256;
      int n = e & 31, kk2 = e >> 5;
      Bs[kk2][n] = B[(size_t)(k0+kk2)*32 + n];
    }
    __syncthreads();
    #pragma unroll
    for (int kk2 = 0; kk2 < 32; kk2++){
      float bb = Bs[kk2][tx];
      #pragma unroll
      for (int i = 0; i < 8; i++)
        acc[i] = fmaf(As[kk2][ty*8 + i], bb, acc[i]);
    }
    __syncthreads();
  }
  #pragma unroll
  for (int i = 0; i < 8; i++)
    O[(size_t)(r0 + ty*8 + i)*32 + tx] = acc[i];
}

// ---------------------------------------------------------------------------
// gemm2: two [2048x512]@[512x512] in one dispatch (blockIdx.z), token-shift
// FUSED into A staging (xk/xv intermediates + k_shift kernel deleted).
// z=0: kgP = (shifted kv, x_k) @ Wk, packed [b][h][tg][c][4]
// z=1: vpP = (shifted kv, x_v) @ Wv, packed
// ---------------------------------------------------------------------------
__global__ __launch_bounds__(256) void gemm2(
  const float* __restrict__ kv,
  const float* __restrict__ x_k, const float* __restrict__ Wk,
  float* __restrict__ kgP,
  const float* __restrict__ x_v, const float* __restrict__ Wv,
  float* __restrict__ vpP)
{
  __shared__ float As[32][68];
  __shared__ float Bs[32][64];
  __shared__ float xm[CC];
  int z = blockIdx.z;
  const float* W = z ? Wv : Wk;
  const float* xmix = z ? x_v : x_k;
  int tid = threadIdx.x;
  for (int c = tid; c < CC; c += 256) xm[c] = xmix[c];
  __syncthreads();
  int tx = tid & 15, ty = tid >> 4;
  int m0 = blockIdx.y*64, n0 = blockIdx.x*64;
  float acc[4][4];
  #pragma unroll
  for (int i=0;i<4;i++)
    #pragma unroll
    for (int j=0;j<4;j++) acc[i][j]=0.f;

  for (int k0 = 0; k0 < 512; k0 += 32){
    #pragma unroll
    for (int i = 0; i < 8; i++){
      int e = tid + i*256;
      int kk = e & 31, mm = e >> 5;
      int m = m0 + mm, col = k0 + kk;
      float cur = kv[(size_t)m*512 + col];
      int t = m & (TT-1);
      float sh = t ? kv[(size_t)(m-1)*512 + col] : 0.f;
      As[kk][mm] = fmaf(sh - cur, xm[col], cur);
    }
    #pragma unroll
    for (int i = 0; i < 8; i++){
      int e = tid + i*256;
      int n = e & 63, kk = e >> 6;
      Bs[kk][n] = W[(size_t)(k0+kk)*512 + n0 + n];
    }
    __syncthreads();
    #pragma unroll
    for (int kk = 0; kk < 32; kk++){
      float a4[4], b4[4];
      #pragma unroll
      for (int i=0;i<4;i++) a4[i] = As[kk][ty*4+i];
      #pragma unroll
      for (int j=0;j<4;j++) b4[j] = Bs[kk][tx*4+j];
      #pragma unroll
      for (int i=0;i<4;i++)
        #pragma unroll
        for (int j=0;j<4;j++) acc[i][j] += a4[i]*b4[j];
    }
    __syncthreads();
  }
  // packed store: rows m..m+3 are 4 consecutive t (u=0..3)
  int m = m0 + ty*4;
  int b = m >> 9, t = m & (TT-1), tg = t >> 2;
  int h = n0 >> 6;
  float* dstB = z ? vpP : kgP;
  float4* dst = (float4*)dstB + ((size_t)(b*HH + h)*TG + tg)*64 + tx*4;
  #pragma unroll
  for (int j=0;j<4;j++)
    dst[j] = make_float4(acc[0][j],acc[1][j],acc[2][j],acc[3][j]);
}

// ---------------------------------------------------------------------------
// k_svn: fused kk-normalize + sv.  Per (b,tg), 512 threads (one channel).
// kk = normalize_per_head(kgP*k_k) via rowsum64_batch<4>; sv = sigm(v0+HV@v2).
// Writes kkP, svP packed.
// ---------------------------------------------------------------------------
__global__ __launch_bounds__(512) void k_svn(
  const float* __restrict__ HV, const float* __restrict__ v2,
  const float* __restrict__ v0, const float* __restrict__ k_k,
  const float* __restrict__ kgP,
  float* __restrict__ svP, float* __restrict__ kkP)
{
  int blk = blockIdx.x;            // b*TG + tg
  int b = blk >> 7, tg = blk & (TG-1);
  int tid = threadIdx.x;           // channel c
  __shared__ float hv[4][32];
  if (tid < 128){
    int u = tid >> 5, d = tid & 31;
    hv[u][d] = HV[((size_t)(b*TT + tg*4 + u))*32 + d];
  }
  __syncthreads();
  int c = tid, h = c >> 6, cc0 = c & 63;
  size_t o = ((size_t)(b*HH + h)*TG + tg)*64 + cc0;
  float4 kg4 = ((const float4*)kgP)[o];
  float kkc = k_k[c];
  float q0 = kg4.x*kkc, q1 = kg4.y*kkc, q2 = kg4.z*kkc, q3 = kg4.w*kkc;
  float ss[4] = {q0*q0, q1*q1, q2*q2, q3*q3};
  rowsum64_batch<4>(ss);            // per-wave = per-head sum
  float4 kkq;
  kkq.x = q0 / fmaxf(sqrtf(ss[0]), 1e-12f);
  kkq.y = q1 / fmaxf(sqrtf(ss[1]), 1e-12f);
  kkq.z = q2 / fmaxf(sqrtf(ss[2]), 1e-12f);
  kkq.w = q3 / fmaxf(sqrtf(ss[3]), 1e-12f);
  ((float4*)kkP)[o] = kkq;
  float v0c = v0[c];
  float s0 = v0c, s1 = v0c, s2 = v0c, s3 = v0c;
  #pragma unroll
  for (int d = 0; d < 32; d++){
    float vc = v2[d*CC + c];
    s0 = fmaf(hv[0][d], vc, s0);
    s1 = fmaf(hv[1][d], vc, s1);
    s2 = fmaf(hv[2][d], vc, s2);
    s3 = fmaf(hv[3][d], vc, s3);
  }
  ((float4*)svP)[o] = make_float4(sigm(s0), sigm(s1), sigm(s2), sigm(s3));
}

// ---------------------------------------------------------------------------
// k_wkb: per (bq,t,c): decay w, k_final, b_vec = kk*a.  R5-proven structure
// (512 threads, one channel each, register-cached w2/a2 columns; natural
// VGPR ~110, no launch_bounds min-waves cap) with kg/kk reads now PACKED
// float4 (raw kg/kkg arrays + k_kk kernel deleted).
// ---------------------------------------------------------------------------
__global__ __launch_bounds__(512) void k_wkb(
  const float* __restrict__ Pw, const float* __restrict__ Pa,
  const float* __restrict__ Qw, const float* __restrict__ Qa,
  const float* __restrict__ w2, const float* __restrict__ a2,
  const float* __restrict__ w0, const float* __restrict__ a0,
  const float* __restrict__ k_a,
  const float* __restrict__ kgP, const float* __restrict__ kkP,
  float* __restrict__ wP, float* __restrict__ kP, float* __restrict__ bP)
{
  int blk = blockIdx.x;              // bq*TG + tg
  int bq = blk >> 7, tg = blk & (TG-1), t0 = tg*4, b = bq >> 3;
  int tid = threadIdx.x;             // = channel c, 0..511
  __shared__ float sth[4][32], sal[4][32];
  if (tid < 256){
    int g = (tid >> 5) & 3, d = tid & 31;
    int pidx = ((b << 9) | (t0 + g))*32 + d;
    if (tid < 128) sth[g][d] = tanhf(Pw[pidx] + Qw[bq*32 + d]);
    else           sal[g][d] = Pa[pidx] + Qa[bq*32 + d];
  }
  __syncthreads();
  int c = tid, h = c >> 6, cc0 = c & 63;
  float wreg[32], areg[32];
  #pragma unroll
  for (int d = 0; d < 32; d++){ wreg[d] = w2[d*CC + c]; areg[d] = a2[d*CC + c]; }
  float w0c = w0[c], a0c = a0[c], kac = k_a[c];
  size_t ob = ((size_t)(b*HH + h)*TG + tg)*64 + cc0;
  float4 kg4 = ((const float4*)kgP)[ob];
  float4 kk4 = ((const float4*)kkP)[ob];
  float kga[4] = {kg4.x, kg4.y, kg4.z, kg4.w};
  float kka[4] = {kk4.x, kk4.y, kk4.z, kk4.w};
  float w4a[4], k4a[4], b4a[4];
  #pragma unroll
  for (int g = 0; g < 4; g++){
    float wa = 0.f, aa = 0.f;
    #pragma unroll
    for (int d = 0; d < 32; d++){
      wa = fmaf(sth[g][d], wreg[d], wa);
      aa = fmaf(sal[g][d], areg[d], aa);
    }
    float a_sig = sigm(a0c + aa);
    w4a[g] = __expf(-0.60653066f * sigm(w0c + wa));
    k4a[g] = kga[g]*(1.f + (a_sig - 1.f)*kac);
    b4a[g] = kka[g]*a_sig;
  }
  size_t o = ((size_t)(bq*HH + h)*TG + tg)*64 + cc0;
  ((float4*)wP)[o] = make_float4(w4a[0],w4a[1],w4a[2],w4a[3]);
  ((float4*)kP)[o] = make_float4(k4a[0],k4a[1],k4a[2],k4a[3]);
  ((float4*)bP)[o] = make_float4(b4a[0],b4a[1],b4a[2],b4a[3]);
}

// ---------------------------------------------------------------------------
// K3: BACKWARD vector scan — R5-measured structure (52 us), verbatim.
//   out = sum_s v_s (k_s . g_s),  g_{s-1} = w_s*g_s - kk_s (b_s . g_s),
//   g_{T-1} = r.
// One wave per (bq,h), lane = channel.  Packed float4 streams, PD=4 group
// register pipeline, sched_barrier(0) pins prefetch in-iteration.
// ---------------------------------------------------------------------------
#define SCAN_STEP(wc,kc,bc,ac,pc,sc,vfc) do{ \
  float vj = fmaf((vfc)-(pc), (sc), (pc)); \
  float rr[2]; rr[0]=(kc)*g; rr[1]=(bc)*g; \
  rowsum64_batch<2>(rr); \
  out = fmaf(rr[0], vj, out); \
  g = fmaf((wc), g, -((ac)*rr[1])); }while(0)

__global__ __launch_bounds__(64, 1) void k_scan(
  const float* __restrict__ wP, const float* __restrict__ kP,
  const float* __restrict__ bP, const float* __restrict__ kkP,
  const float* __restrict__ vpP, const float* __restrict__ svP,
  const float* __restrict__ vfirst,
  const float* __restrict__ rrow, const float* __restrict__ grow,
  const float* __restrict__ r_k, const float* __restrict__ ln_w,
  const float* __restrict__ ln_b, float* __restrict__ xo)
{
  int blk = blockIdx.x; int bq = blk >> 3, h = blk & 7, b = bq >> 3;
  int lane = threadIdx.x & 63;

  // per-(bq,h) packed bases: TG*64 float4s each
  const float4* wp4 = (const float4*)wP  + ((size_t)(bq*HH + h))*TG*64 + lane;
  const float4* kp4 = (const float4*)kP  + ((size_t)(bq*HH + h))*TG*64 + lane;
  const float4* bp4 = (const float4*)bP  + ((size_t)(bq*HH + h))*TG*64 + lane;
  const float4* ap4 = (const float4*)kkP + ((size_t)(b*HH + h))*TG*64 + lane;
  const float4* pp4 = (const float4*)vpP + ((size_t)(b*HH + h))*TG*64 + lane;
  const float4* sp4 = (const float4*)svP + ((size_t)(b*HH + h))*TG*64 + lane;
  const float*  pvf = vfirst + (size_t)bq*TT*CC + h*NN + lane;

  float g   = rrow[(size_t)bq*CC + h*NN + lane];   // g_{T-1} = r
  float out = 0.f;

  constexpr int PD = 4;                // prefetch depth, in groups of 4 steps
  float4 fw[PD], fk[PD], fb[PD], fa[PD], fp[PD], fs[PD];
  float fv0[PD], fv1[PD], fv2[PD], fv3[PD];
  #pragma unroll
  for (int d = 0; d < PD; ++d){
    int gg = TG-1 - d; int go = gg*64;
    fw[d]=wp4[go]; fk[d]=kp4[go]; fb[d]=bp4[go]; fa[d]=ap4[go];
    fp[d]=pp4[go]; fs[d]=sp4[go];
    const float* pv = pvf + (size_t)(4*gg)*CC;
    fv0[d]=pv[0]; fv1[d]=pv[CC]; fv2[d]=pv[2*CC]; fv3[d]=pv[3*CC];
  }

  #pragma unroll 1
  for (int gb = 0; gb < TG; gb += PD){
    #pragma unroll
    for (int sl = 0; sl < PD; ++sl){
      int gi = TG-1 - (gb + sl);       // current group (descending)
      // snapshot slot
      float4 w4=fw[sl], k4=fk[sl], b4=fb[sl], a4=fa[sl], p4=fp[sl], s4=fs[sl];
      float v3=fv3[sl], v2_=fv2[sl], v1_=fv1[sl], v0_=fv0[sl];
      // prefetch group gi-PD into slot sl (clamped; dup loads harmless)
      int gp = gi - PD; gp = gp < 0 ? 0 : gp; int go = gp*64;
      fw[sl]=wp4[go]; fk[sl]=kp4[go]; fb[sl]=bp4[go]; fa[sl]=ap4[go];
      fp[sl]=pp4[go]; fs[sl]=sp4[go];
      { const float* pv = pvf + (size_t)(4*gp)*CC;
        fv0[sl]=pv[0]; fv1[sl]=pv[CC]; fv2[sl]=pv[2*CC]; fv3[sl]=pv[3*CC]; }
      __builtin_amdgcn_sched_barrier(0);   // pin loads in this iteration
      // 4 steps, s = 4*gi+3 .. 4*gi+0
      SCAN_STEP(w4.w,k4.w,b4.w,a4.w,p4.w,s4.w,v3);
      SCAN_STEP(w4.z,k4.z,b4.z,a4.z,p4.z,s4.z,v2_);
      SCAN_STEP(w4.y,k4.y,b4.y,a4.y,p4.y,s4.y,v1_);
      SCAN_STEP(w4.x,k4.x,b4.x,a4.x,p4.x,s4.x,v0_);
    }
  }

  // epilogue: groupnorm over head + rk*v term + gate (per-lane channel)
  {
    float mean = wsum(out) * (1.f/NN);
    float dv = out - mean;
    float var = wsum(dv*dv) * (1.f/NN);
    float yn = dv * rsqrtf(var + 6.4e-4f);   // GN_EPS = 1e-5*64
    int c = h*NN + lane;
    float y2 = yn * ln_w[c] + ln_b[c];
    int goT = (TG-1)*64;
    float kl  = kp4[goT].w;                  // k at t = T-1
    float rl  = rrow[(size_t)bq*CC + c];
    float rk  = wsum(rl*kl*r_k[c]);
    float vp_ = pp4[goT].w, sv_ = sp4[goT].w;
    float vf_ = pvf[(size_t)(TT-1)*CC];
    float v_i = fmaf(vf_ - vp_, sv_, vp_);   // v_{T-1}
    float res = (y2 + rk*v_i) * grow[(size_t)bq*CC + c];
    xo[bq*CC + c] = res;
  }
}

// ---------------------------------------------------------------------------
// K4: out[bq,co] = xo[bq,:] @ Wo[:,co]
// ---------------------------------------------------------------------------
__global__ __launch_bounds__(256) void k_out(
  const float* __restrict__ xo, const float* __restrict__ Wo,
  float* __restrict__ outp)
{
  int bq = blockIdx.y; int co0 = blockIdx.x*64;
  int tid = threadIdx.x, tx = tid & 63, ty = tid >> 6;
  __shared__ float row[CC];
  __shared__ float red[4][64];
  row[tid]     = xo[bq*CC + tid];
  row[tid+256] = xo[bq*CC + tid + 256];
  __syncthreads();
  float p = 0.f;
  for (int i = 0; i < 128; i++){
    int c = ty*128 + i;
    p = fmaf(row[c], Wo[(size_t)c*CC + co0 + tx], p);
  }
  red[ty][tx] = p;
  __syncthreads();
  if (ty == 0)
    outp[bq*CC + co0 + tx] = (red[0][tx]+red[1][tx])+(red[2][tx]+red[3][tx]);
}

// ---------------------------------------------------------------------------
extern "C" void kernel_launch(void* const* d_in, const int* in_sizes, int n_in,
                              void* d_out, int out_size, void* d_ws, size_t ws_size,
                              hipStream_t stream)
{
  const float* q   = (const float*)d_in[0];
  const float* kv  = (const float*)d_in[1];
  const float* vf  = (const float*)d_in[2];
  const float* x_r = (const float*)d_in[3];
  const float* x_w = (const float*)d_in[4];
  const float* x_k = (const float*)d_in[5];
  const float* x_v = (const float*)d_in[6];
  const float* x_a = (const float*)d_in[7];
  const float* x_g = (const float*)d_in[8];
  const float* w0  = (const float*)d_in[9];
  const float* w1  = (const float*)d_in[10];
  const float* w2  = (const float*)d_in[11];
  const float* a0  = (const float*)d_in[12];
  const float* a1  = (const float*)d_in[13];
  const float* a2  = (const float*)d_in[14];
  const float* v0  = (const float*)d_in[15];
  const float* v1  = (const float*)d_in[16];
  const float* v2  = (const float*)d_in[17];
  const float* g1  = (const float*)d_in[18];
  const float* g2  = (const float*)d_in[19];
  const float* k_k = (const float*)d_in[20];
  const float* k_a = (const float*)d_in[21];
  const float* r_k = (const float*)d_in[22];
  const float* Wr  = (const float*)d_in[23];
  const float* Wk  = (const float*)d_in[24];
  const float* Wv  = (const float*)d_in[25];
  const float* Wo  = (const float*)d_in[26];
  const float* lnw = (const float*)d_in[27];
  const float* lnb = (const float*)d_in[28];
  float* outp = (float*)d_out;
  float* ws = (float*)d_ws;

  // workspace layout (floats)
  float* kgP = ws + 2097152;   // k raw, packed [b][h][tg][c][4]
  float* vpP = ws + 3145728;   // v_pre, packed
  float* svP = ws + 4194304;   // sigmoid lerp factor, packed
  float* kkP = ws + 5242880;   // normalized kk, packed
  float* Pw  = ws + 6291456;   // 4*512*32
  float* Pa  = ws + 6356992;
  float* Qw  = ws + 6422528;   // 32*32
  float* Qa  = ws + 6423552;
  float* HV  = ws + 6424576;   // 4*512*32
  float* rr  = ws + 7473152;   // 32*512
  float* gr  = ws + 7489536;
  float* xo  = ws + 7505920;
  float* wP  = ws + 7522304;   // 32*512*512 decay, packed [bq][h][tg][c][4]
  float* kP  = ws + 15910912;  // k_final, packed
  float* bP  = ws + 24299520;  // kk*a, packed
  float* xrw = ws + 32688128;  // 32*512
  float* ghw = ws + 32704512;  // 32*96

  // v_first passthrough (tuple output #2)
  hipMemcpyAsync(outp + BQ*CC, vf,
                 (size_t)BQ*TT*CC*sizeof(float), hipMemcpyDeviceToDevice, stream);

  k_prep<<<32, 256, 0, stream>>>(q, kv, x_r, x_w, x_a, x_g, w1, a1, g1,
                                 Qw, Qa, ghw, xrw);
  k_rg<<<dim3(8, 32), 256, 0, stream>>>(xrw, ghw, Wr, g2, rr, gr);
  gemm2<<<dim3(8, 32, 2), 256, 0, stream>>>(kv, x_k, Wk, kgP, x_v, Wv, vpP);
  k_pgemm<<<dim3(32, 3), 256, 0, stream>>>(kv, x_w, x_a, x_v, w1, a1, v1,
                                           Pw, Pa, HV);
  k_svn<<<NB*TG, 512, 0, stream>>>(HV, v2, v0, k_k, kgP, svP, kkP);
  k_wkb<<<BQ*TG, 512, 0, stream>>>(Pw, Pa, Qw, Qa, w2, a2, w0, a0, k_a,
                                   kgP, kkP, wP, kP, bP);
  k_scan<<<BQ*HH, 64, 0, stream>>>(wP, kP, bP, kkP, vpP, svP, vf, rr, gr, r_k,
                                   lnw, lnb, xo);
  k_out<<<dim3(8, 32), 256, 0, stream>>>(xo, Wo, outp);
}

// Round 9
// 388.460 us; speedup vs baseline: 1.0604x; 1.0604x over previous
//
#include <hip/hip_runtime.h>
#include <cstdint>

// Problem constants
#define TT 512   // KVLEN
#define CC 512   // C
#define HH 8     // heads
#define NN 64    // head dim
#define BQ 32    // BATCH*QLEN
#define NB 4     // BATCH
#define TG 128   // TT/4 packed groups

__device__ __forceinline__ float sigm(float x){ return 1.f/(1.f+__expf(-x)); }

__device__ __forceinline__ float wsum(float x){
  #pragma unroll
  for (int o=32;o;o>>=1) x += __shfl_xor(x, o, 64);
  return x;
}

// ---------------------------------------------------------------------------
// Batched wave64 row-sum, VALU-only: DPP row_ror tree + permlane16/32 swap.
// ---------------------------------------------------------------------------
template<int NR>
__device__ __forceinline__ void rowsum64_batch(float* x){
  #pragma unroll
  for (int i=0;i<NR;i++)
    x[i] += __int_as_float(__builtin_amdgcn_mov_dpp(__float_as_int(x[i]), 0x121, 0xf, 0xf, true));
  #pragma unroll
  for (int i=0;i<NR;i++)
    x[i] += __int_as_float(__builtin_amdgcn_mov_dpp(__float_as_int(x[i]), 0x122, 0xf, 0xf, true));
  #pragma unroll
  for (int i=0;i<NR;i++)
    x[i] += __int_as_float(__builtin_amdgcn_mov_dpp(__float_as_int(x[i]), 0x124, 0xf, 0xf, true));
  #pragma unroll
  for (int i=0;i<NR;i++)
    x[i] += __int_as_float(__builtin_amdgcn_mov_dpp(__float_as_int(x[i]), 0x128, 0xf, 0xf, true));
  float y[NR];
  #pragma unroll
  for (int i=0;i<NR;i++) asm("v_mov_b32 %0, %1" : "=v"(y[i]) : "v"(x[i]));
  #pragma unroll
  for (int i=0;i<NR;i++) asm("v_permlane16_swap_b32 %0, %1" : "+v"(x[i]), "+v"(y[i]));
  #pragma unroll
  for (int i=0;i<NR;i++) x[i] += y[i];
  #pragma unroll
  for (int i=0;i<NR;i++) asm("v_mov_b32 %0, %1" : "=v"(y[i]) : "v"(x[i]));
  #pragma unroll
  for (int i=0;i<NR;i++) asm("v_permlane32_swap_b32 %0, %1" : "+v"(x[i]), "+v"(y[i]));
  #pragma unroll
  for (int i=0;i<NR;i++) x[i] += y[i];
}

// ---------------------------------------------------------------------------
// k_prep: per-bq small dots (32 blocks): Qw[bq,32], Qa[bq,32], gh[bq,96],
// and xr row -> workspace.
// ---------------------------------------------------------------------------
__global__ __launch_bounds__(256) void k_prep(
  const float* __restrict__ q, const float* __restrict__ kv,
  const float* __restrict__ x_r, const float* __restrict__ x_w,
  const float* __restrict__ x_a, const float* __restrict__ x_g,
  const float* __restrict__ w1, const float* __restrict__ a1,
  const float* __restrict__ g1,
  float* __restrict__ Qw, float* __restrict__ Qa,
  float* __restrict__ ghw, float* __restrict__ xrw)
{
  int bq = blockIdx.x, b = bq >> 3, tid = threadIdx.x;
  int wave = tid >> 6, lane = tid & 63;
  __shared__ float qxw[CC], qxa[CC], sxg[CC];
  for (int c = tid; c < CC; c += 256){
    float qv = q[bq*CC + c];
    float kl = kv[((size_t)b*TT + (TT-1))*CC + c];
    xrw[bq*CC + c] = kl + (qv - kl)*x_r[c];
    sxg[c] = kl + (qv - kl)*x_g[c];
    qxw[c] = qv*x_w[c];
    qxa[c] = qv*x_a[c];
  }
  __syncthreads();
  for (int dot = wave; dot < 160; dot += 4){
    const float* buf; const float* W; int ld, dd;
    if (dot < 32)      { buf = qxw; W = w1; ld = 32; dd = dot; }
    else if (dot < 64) { buf = qxa; W = a1; ld = 32; dd = dot-32; }
    else               { buf = sxg; W = g1; ld = 96; dd = dot-64; }
    float s = 0.f;
    #pragma unroll
    for (int m = 0; m < 8; m++){
      int c = m*64 + lane;
      s = fmaf(buf[c], W[c*ld + dd], s);
    }
    s = wsum(s);
    if (lane == 0){
      if (dot < 32)      Qw[bq*32 + dd] = s;
      else if (dot < 64) Qa[bq*32 + dd] = s;
      else               ghw[bq*96 + dd] = sigm(s);
    }
  }
}

// ---------------------------------------------------------------------------
// k_rg: rrow[bq,co] = xr[bq,:]@Wr[:,co], grow[bq,co] = gh[bq,:]@g2[:,co]
// ---------------------------------------------------------------------------
__global__ __launch_bounds__(256) void k_rg(
  const float* __restrict__ xrw, const float* __restrict__ ghw,
  const float* __restrict__ Wr, const float* __restrict__ g2,
  float* __restrict__ rrow, float* __restrict__ grow)
{
  int bq = blockIdx.y; int co0 = blockIdx.x*64;
  int tid = threadIdx.x, tx = tid & 63, ty = tid >> 6;
  __shared__ float sxr[CC];
  __shared__ float sgh[96];
  __shared__ float red[4][64];
  sxr[tid]     = xrw[bq*CC + tid];
  sxr[tid+256] = xrw[bq*CC + tid + 256];
  if (tid < 96) sgh[tid] = ghw[bq*96 + tid];
  __syncthreads();
  float p = 0.f;
  for (int i = 0; i < 128; i++){
    int c = ty*128 + i;
    p = fmaf(sxr[c], Wr[(size_t)c*CC + co0 + tx], p);
  }
  red[ty][tx] = p;
  float pg = 0.f;
  for (int d = ty*24; d < ty*24 + 24; d++)
    pg = fmaf(sgh[d], g2[(size_t)d*CC + co0 + tx], pg);
  __syncthreads();
  if (ty == 0)
    rrow[bq*CC + co0 + tx] = (red[0][tx]+red[1][tx])+(red[2][tx]+red[3][tx]);
  __syncthreads();
  red[ty][tx] = pg;
  __syncthreads();
  if (ty == 0)
    grow[bq*CC + co0 + tx] = (red[0][tx]+red[1][tx])+(red[2][tx]+red[3][tx]);
}

// ---------------------------------------------------------------------------
// k_shift: elementwise token-shift mix: xk, xv.  float4, coalesced.
// (R9: restored — fusing this into the small-grid GEMMs was a measured
// regression: k_pgemm 72.9us @ 2.8% VALUBusy, pure latency serialization.)
// ---------------------------------------------------------------------------
__global__ __launch_bounds__(256) void k_shift(
  const float* __restrict__ kv, const float* __restrict__ x_k,
  const float* __restrict__ x_v,
  float* __restrict__ xk, float* __restrict__ xv)
{
  int g = blockIdx.x*256 + threadIdx.x;      // float4 index, [0, 262144)
  int bt = g >> 7, t = bt & (TT-1), c4 = g & 127;
  const float4* kv4 = (const float4*)kv;
  float4 cur = kv4[g];
  float4 sh  = t ? kv4[g-128] : make_float4(0.f,0.f,0.f,0.f);
  float4 kc  = ((const float4*)x_k)[c4];
  float4 vc  = ((const float4*)x_v)[c4];
  float4 ok, ov;
  ok.x = cur.x + (sh.x-cur.x)*kc.x; ov.x = cur.x + (sh.x-cur.x)*vc.x;
  ok.y = cur.y + (sh.y-cur.y)*kc.y; ov.y = cur.y + (sh.y-cur.y)*vc.y;
  ok.z = cur.z + (sh.z-cur.z)*kc.z; ov.z = cur.z + (sh.z-cur.z)*vc.z;
  ok.w = cur.w + (sh.w-cur.w)*kc.w; ov.w = cur.w + (sh.w-cur.w)*vc.w;
  ((float4*)xk)[g] = ok;
  ((float4*)xv)[g] = ov;
}

// ---------------------------------------------------------------------------
// k_pgemm: three [2048x512]@[512x32] products (Pw, Pa, HV), tiled.
// R5-measured structure: reads kv (mat 0/1) or precomputed xv (mat 2).
// ---------------------------------------------------------------------------
__global__ __launch_bounds__(256) void k_pgemm(
  const float* __restrict__ kv, const float* __restrict__ xv,
  const float* __restrict__ x_w, const float* __restrict__ x_a,
  const float* __restrict__ w1, const float* __restrict__ a1,
  const float* __restrict__ v1,
  float* __restrict__ Pw, float* __restrict__ Pa, float* __restrict__ HV)
{
  int mat = blockIdx.y;
  int r0 = blockIdx.x * 64;
  const float* A = (mat == 2) ? xv : kv;
  const float* B = (mat == 0) ? w1 : (mat == 1) ? a1 : v1;
  float* O       = (mat == 0) ? Pw : (mat == 1) ? Pa : HV;
  int tid = threadIdx.x;
  __shared__ float As[32][65];
  __shared__ float Bs[32][32];
  __shared__ float scl[CC];
  for (int c = tid; c < CC; c += 256)
    scl[c] = (mat == 0) ? (1.f - x_w[c]) : (mat == 1) ? (1.f - x_a[c]) : 1.f;
  __syncthreads();
  int tx = tid & 31, ty = tid >> 5;
  float acc[8];
  #pragma unroll
  for (int i = 0; i < 8; i++) acc[i] = 0.f;
  for (int k0 = 0; k0 < 512; k0 += 32){
    #pragma unroll
    for (int p = 0; p < 8; p++){
      int e = tid + p*256;
      int kk2 = e & 31, r = e >> 5;
      As[kk2][r] = A[(size_t)(r0+r)*512 + k0 + kk2] * scl[k0 + kk2];
    }
    #pragma unroll
    for (int p = 0; p < 4; p++){
      int e = tid + p*256;
      int n = e & 31, kk2 = e >> 5;
      Bs[kk2][n] = B[(size_t)(k0+kk2)*32 + n];
    }
    __syncthreads();
    #pragma unroll
    for (int kk2 = 0; kk2 < 32; kk2++){
      float bb = Bs[kk2][tx];
      #pragma unroll
      for (int i = 0; i < 8; i++)
        acc[i] = fmaf(As[kk2][ty*8 + i], bb, acc[i]);
    }
    __syncthreads();
  }
  #pragma unroll
  for (int i = 0; i < 8; i++)
    O[(size_t)(r0 + ty*8 + i)*32 + tx] = acc[i];
}

// ---------------------------------------------------------------------------
// gemm2: two [2048x512]@[512x512] in one dispatch (blockIdx.z).
// BOTH outputs packed [b][h][tg][c][4]: z=0 -> kgP (from xk@Wk),
// z=1 -> vpP (from xv@Wv).  Reads precomputed xk/xv (R9 revert).
// ---------------------------------------------------------------------------
__global__ __launch_bounds__(256) void gemm2(
  const float* __restrict__ A0, const float* __restrict__ W0, float* __restrict__ kgP,
  const float* __restrict__ A1, const float* __restrict__ W1, float* __restrict__ vpP)
{
  __shared__ float As[32][68];
  __shared__ float Bs[32][64];
  int z = blockIdx.z;
  const float* A = z ? A1 : A0;
  const float* W = z ? W1 : W0;
  int tid = threadIdx.x;
  int tx = tid & 15, ty = tid >> 4;
  int m0 = blockIdx.y*64, n0 = blockIdx.x*64;
  float acc[4][4];
  #pragma unroll
  for (int i=0;i<4;i++)
    #pragma unroll
    for (int j=0;j<4;j++) acc[i][j]=0.f;

  for (int k0 = 0; k0 < 512; k0 += 32){
    #pragma unroll
    for (int i = 0; i < 8; i++){
      int e = tid + i*256;
      int kk = e & 31, m = e >> 5;
      As[kk][m] = A[(size_t)(m0+m)*512 + k0 + kk];
    }
    #pragma unroll
    for (int i = 0; i < 8; i++){
      int e = tid + i*256;
      int n = e & 63, kk = e >> 6;
      Bs[kk][n] = W[(size_t)(k0+kk)*512 + n0 + n];
    }
    __syncthreads();
    #pragma unroll
    for (int kk = 0; kk < 32; kk++){
      float a4[4], b4[4];
      #pragma unroll
      for (int i=0;i<4;i++) a4[i] = As[kk][ty*4+i];
      #pragma unroll
      for (int j=0;j<4;j++) b4[j] = Bs[kk][tx*4+j];
      #pragma unroll
      for (int i=0;i<4;i++)
        #pragma unroll
        for (int j=0;j<4;j++) acc[i][j] += a4[i]*b4[j];
    }
    __syncthreads();
  }
  // packed store: rows m..m+3 are 4 consecutive t (u=0..3)
  int m = m0 + ty*4;
  int b = m >> 9, t = m & (TT-1), tg = t >> 2;
  int h = n0 >> 6;
  float* dstB = z ? vpP : kgP;
  float4* dst = (float4*)dstB + ((size_t)(b*HH + h)*TG + tg)*64 + tx*4;
  #pragma unroll
  for (int j=0;j<4;j++)
    dst[j] = make_float4(acc[0][j],acc[1][j],acc[2][j],acc[3][j]);
}

// ---------------------------------------------------------------------------
// k_svn: fused kk-normalize + sv.  Per (b,tg), 512 threads (one channel).
// kk = normalize_per_head(kgP*k_k) via rowsum64_batch<4>; sv = sigm(v0+HV@v2).
// Writes kkP, svP packed.
// ---------------------------------------------------------------------------
__global__ __launch_bounds__(512) void k_svn(
  const float* __restrict__ HV, const float* __restrict__ v2,
  const float* __restrict__ v0, const float* __restrict__ k_k,
  const float* __restrict__ kgP,
  float* __restrict__ svP, float* __restrict__ kkP)
{
  int blk = blockIdx.x;            // b*TG + tg
  int b = blk >> 7, tg = blk & (TG-1);
  int tid = threadIdx.x;           // channel c
  __shared__ float hv[4][32];
  if (tid < 128){
    int u = tid >> 5, d = tid & 31;
    hv[u][d] = HV[((size_t)(b*TT + tg*4 + u))*32 + d];
  }
  __syncthreads();
  int c = tid, h = c >> 6, cc0 = c & 63;
  size_t o = ((size_t)(b*HH + h)*TG + tg)*64 + cc0;
  float4 kg4 = ((const float4*)kgP)[o];
  float kkc = k_k[c];
  float q0 = kg4.x*kkc, q1 = kg4.y*kkc, q2 = kg4.z*kkc, q3 = kg4.w*kkc;
  float ss[4] = {q0*q0, q1*q1, q2*q2, q3*q3};
  rowsum64_batch<4>(ss);            // per-wave = per-head sum
  float4 kkq;
  kkq.x = q0 / fmaxf(sqrtf(ss[0]), 1e-12f);
  kkq.y = q1 / fmaxf(sqrtf(ss[1]), 1e-12f);
  kkq.z = q2 / fmaxf(sqrtf(ss[2]), 1e-12f);
  kkq.w = q3 / fmaxf(sqrtf(ss[3]), 1e-12f);
  ((float4*)kkP)[o] = kkq;
  float v0c = v0[c];
  float s0 = v0c, s1 = v0c, s2 = v0c, s3 = v0c;
  #pragma unroll
  for (int d = 0; d < 32; d++){
    float vc = v2[d*CC + c];
    s0 = fmaf(hv[0][d], vc, s0);
    s1 = fmaf(hv[1][d], vc, s1);
    s2 = fmaf(hv[2][d], vc, s2);
    s3 = fmaf(hv[3][d], vc, s3);
  }
  ((float4*)svP)[o] = make_float4(sigm(s0), sigm(s1), sigm(s2), sigm(s3));
}

// ---------------------------------------------------------------------------
// k_wkb: per (bq,t,c): decay w, k_final, b_vec = kk*a.  R5-proven structure
// (512 threads, one channel each, register-cached w2/a2 columns), kg/kk
// reads packed float4.
// ---------------------------------------------------------------------------
__global__ __launch_bounds__(512) void k_wkb(
  const float* __restrict__ Pw, const float* __restrict__ Pa,
  const float* __restrict__ Qw, const float* __restrict__ Qa,
  const float* __restrict__ w2, const float* __restrict__ a2,
  const float* __restrict__ w0, const float* __restrict__ a0,
  const float* __restrict__ k_a,
  const float* __restrict__ kgP, const float* __restrict__ kkP,
  float* __restrict__ wP, float* __restrict__ kP, float* __restrict__ bP)
{
  int blk = blockIdx.x;              // bq*TG + tg
  int bq = blk >> 7, tg = blk & (TG-1), t0 = tg*4, b = bq >> 3;
  int tid = threadIdx.x;             // = channel c, 0..511
  __shared__ float sth[4][32], sal[4][32];
  if (tid < 256){
    int g = (tid >> 5) & 3, d = tid & 31;
    int pidx = ((b << 9) | (t0 + g))*32 + d;
    if (tid < 128) sth[g][d] = tanhf(Pw[pidx] + Qw[bq*32 + d]);
    else           sal[g][d] = Pa[pidx] + Qa[bq*32 + d];
  }
  __syncthreads();
  int c = tid, h = c >> 6, cc0 = c & 63;
  float wreg[32], areg[32];
  #pragma unroll
  for (int d = 0; d < 32; d++){ wreg[d] = w2[d*CC + c]; areg[d] = a2[d*CC + c]; }
  float w0c = w0[c], a0c = a0[c], kac = k_a[c];
  size_t ob = ((size_t)(b*HH + h)*TG + tg)*64 + cc0;
  float4 kg4 = ((const float4*)kgP)[ob];
  float4 kk4 = ((const float4*)kkP)[ob];
  float kga[4] = {kg4.x, kg4.y, kg4.z, kg4.w};
  float kka[4] = {kk4.x, kk4.y, kk4.z, kk4.w};
  float w4a[4], k4a[4], b4a[4];
  #pragma unroll
  for (int g = 0; g < 4; g++){
    float wa = 0.f, aa = 0.f;
    #pragma unroll
    for (int d = 0; d < 32; d++){
      wa = fmaf(sth[g][d], wreg[d], wa);
      aa = fmaf(sal[g][d], areg[d], aa);
    }
    float a_sig = sigm(a0c + aa);
    w4a[g] = __expf(-0.60653066f * sigm(w0c + wa));
    k4a[g] = kga[g]*(1.f + (a_sig - 1.f)*kac);
    b4a[g] = kka[g]*a_sig;
  }
  size_t o = ((size_t)(bq*HH + h)*TG + tg)*64 + cc0;
  ((float4*)wP)[o] = make_float4(w4a[0],w4a[1],w4a[2],w4a[3]);
  ((float4*)kP)[o] = make_float4(k4a[0],k4a[1],k4a[2],k4a[3]);
  ((float4*)bP)[o] = make_float4(b4a[0],b4a[1],b4a[2],b4a[3]);
}

// ---------------------------------------------------------------------------
// K3: BACKWARD vector scan — R5-measured per-wave structure, R9 geometry:
// ONE BLOCK = 512 threads = 8 waves = all 8 heads of one bq.  Waves round-
// robin onto the CU's 4 SIMDs -> 2 independent chains per SIMD, so the HW
// interleaves one chain's instructions through the other's DPP-dependency
// bubbles (R5 counters: busy SIMD was ~56% issue / ~44% dep-stall; R6/R7
// attacked issue count and failed — stall is the target).  No barriers in
// the loop; per-wave code identical to R5.
// ---------------------------------------------------------------------------
#define SCAN_STEP(wc,kc,bc,ac,pc,sc,vfc) do{ \
  float vj = fmaf((vfc)-(pc), (sc), (pc)); \
  float rr[2]; rr[0]=(kc)*g; rr[1]=(bc)*g; \
  rowsum64_batch<2>(rr); \
  out = fmaf(rr[0], vj, out); \
  g = fmaf((wc), g, -((ac)*rr[1])); }while(0)

__global__ __launch_bounds__(512, 1) void k_scan(
  const float* __restrict__ wP, const float* __restrict__ kP,
  const float* __restrict__ bP, const float* __restrict__ kkP,
  const float* __restrict__ vpP, const float* __restrict__ svP,
  const float* __restrict__ vfirst,
  const float* __restrict__ rrow, const float* __restrict__ grow,
  const float* __restrict__ r_k, const float* __restrict__ ln_w,
  const float* __restrict__ ln_b, float* __restrict__ xo)
{
  int wave = threadIdx.x >> 6;
  int lane = threadIdx.x & 63;
  int bq = blockIdx.x, h = wave, b = bq >> 3;

  // per-(bq,h) packed bases: TG*64 float4s each
  const float4* wp4 = (const float4*)wP  + ((size_t)(bq*HH + h))*TG*64 + lane;
  const float4* kp4 = (const float4*)kP  + ((size_t)(bq*HH + h))*TG*64 + lane;
  const float4* bp4 = (const float4*)bP  + ((size_t)(bq*HH + h))*TG*64 + lane;
  const float4* ap4 = (const float4*)kkP + ((size_t)(b*HH + h))*TG*64 + lane;
  const float4* pp4 = (const float4*)vpP + ((size_t)(b*HH + h))*TG*64 + lane;
  const float4* sp4 = (const float4*)svP + ((size_t)(b*HH + h))*TG*64 + lane;
  const float*  pvf = vfirst + (size_t)bq*TT*CC + h*NN + lane;

  float g   = rrow[(size_t)bq*CC + h*NN + lane];   // g_{T-1} = r
  float out = 0.f;

  constexpr int PD = 4;                // prefetch depth, in groups of 4 steps
  float4 fw[PD], fk[PD], fb[PD], fa[PD], fp[PD], fs[PD];
  float fv0[PD], fv1[PD], fv2[PD], fv3[PD];
  #pragma unroll
  for (int d = 0; d < PD; ++d){
    int gg = TG-1 - d; int go = gg*64;
    fw[d]=wp4[go]; fk[d]=kp4[go]; fb[d]=bp4[go]; fa[d]=ap4[go];
    fp[d]=pp4[go]; fs[d]=sp4[go];
    const float* pv = pvf + (size_t)(4*gg)*CC;
    fv0[d]=pv[0]; fv1[d]=pv[CC]; fv2[d]=pv[2*CC]; fv3[d]=pv[3*CC];
  }

  #pragma unroll 1
  for (int gb = 0; gb < TG; gb += PD){
    #pragma unroll
    for (int sl = 0; sl < PD; ++sl){
      int gi = TG-1 - (gb + sl);       // current group (descending)
      // snapshot slot
      float4 w4=fw[sl], k4=fk[sl], b4=fb[sl], a4=fa[sl], p4=fp[sl], s4=fs[sl];
      float v3=fv3[sl], v2_=fv2[sl], v1_=fv1[sl], v0_=fv0[sl];
      // prefetch group gi-PD into slot sl (clamped; dup loads harmless)
      int gp = gi - PD; gp = gp < 0 ? 0 : gp; int go = gp*64;
      fw[sl]=wp4[go]; fk[sl]=kp4[go]; fb[sl]=bp4[go]; fa[sl]=ap4[go];
      fp[sl]=pp4[go]; fs[sl]=sp4[go];
      { const float* pv = pvf + (size_t)(4*gp)*CC;
        fv0[sl]=pv[0]; fv1[sl]=pv[CC]; fv2[sl]=pv[2*CC]; fv3[sl]=pv[3*CC]; }
      __builtin_amdgcn_sched_barrier(0);   // pin loads in this iteration
      // 4 steps, s = 4*gi+3 .. 4*gi+0
      SCAN_STEP(w4.w,k4.w,b4.w,a4.w,p4.w,s4.w,v3);
      SCAN_STEP(w4.z,k4.z,b4.z,a4.z,p4.z,s4.z,v2_);
      SCAN_STEP(w4.y,k4.y,b4.y,a4.y,p4.y,s4.y,v1_);
      SCAN_STEP(w4.x,k4.x,b4.x,a4.x,p4.x,s4.x,v0_);
    }
  }

  // epilogue: groupnorm over head + rk*v term + gate (per-lane channel)
  {
    float mean = wsum(out) * (1.f/NN);
    float dv = out - mean;
    float var = wsum(dv*dv) * (1.f/NN);
    float yn = dv * rsqrtf(var + 6.4e-4f);   // GN_EPS = 1e-5*64
    int c = h*NN + lane;
    float y2 = yn * ln_w[c] + ln_b[c];
    int goT = (TG-1)*64;
    float kl  = kp4[goT].w;                  // k at t = T-1
    float rl  = rrow[(size_t)bq*CC + c];
    float rk  = wsum(rl*kl*r_k[c]);
    float vp_ = pp4[goT].w, sv_ = sp4[goT].w;
    float vf_ = pvf[(size_t)(TT-1)*CC];
    float v_i = fmaf(vf_ - vp_, sv_, vp_);   // v_{T-1}
    float res = (y2 + rk*v_i) * grow[(size_t)bq*CC + c];
    xo[bq*CC + c] = res;
  }
}

// ---------------------------------------------------------------------------
// K4: out[bq,co] = xo[bq,:] @ Wo[:,co]
// ---------------------------------------------------------------------------
__global__ __launch_bounds__(256) void k_out(
  const float* __restrict__ xo, const float* __restrict__ Wo,
  float* __restrict__ outp)
{
  int bq = blockIdx.y; int co0 = blockIdx.x*64;
  int tid = threadIdx.x, tx = tid & 63, ty = tid >> 6;
  __shared__ float row[CC];
  __shared__ float red[4][64];
  row[tid]     = xo[bq*CC + tid];
  row[tid+256] = xo[bq*CC + tid + 256];
  __syncthreads();
  float p = 0.f;
  for (int i = 0; i < 128; i++){
    int c = ty*128 + i;
    p = fmaf(row[c], Wo[(size_t)c*CC + co0 + tx], p);
  }
  red[ty][tx] = p;
  __syncthreads();
  if (ty == 0)
    outp[bq*CC + co0 + tx] = (red[0][tx]+red[1][tx])+(red[2][tx]+red[3][tx]);
}

// ---------------------------------------------------------------------------
extern "C" void kernel_launch(void* const* d_in, const int* in_sizes, int n_in,
                              void* d_out, int out_size, void* d_ws, size_t ws_size,
                              hipStream_t stream)
{
  const float* q   = (const float*)d_in[0];
  const float* kv  = (const float*)d_in[1];
  const float* vf  = (const float*)d_in[2];
  const float* x_r = (const float*)d_in[3];
  const float* x_w = (const float*)d_in[4];
  const float* x_k = (const float*)d_in[5];
  const float* x_v = (const float*)d_in[6];
  const float* x_a = (const float*)d_in[7];
  const float* x_g = (const float*)d_in[8];
  const float* w0  = (const float*)d_in[9];
  const float* w1  = (const float*)d_in[10];
  const float* w2  = (const float*)d_in[11];
  const float* a0  = (const float*)d_in[12];
  const float* a1  = (const float*)d_in[13];
  const float* a2  = (const float*)d_in[14];
  const float* v0  = (const float*)d_in[15];
  const float* v1  = (const float*)d_in[16];
  const float* v2  = (const float*)d_in[17];
  const float* g1  = (const float*)d_in[18];
  const float* g2  = (const float*)d_in[19];
  const float* k_k = (const float*)d_in[20];
  const float* k_a = (const float*)d_in[21];
  const float* r_k = (const float*)d_in[22];
  const float* Wr  = (const float*)d_in[23];
  const float* Wk  = (const float*)d_in[24];
  const float* Wv  = (const float*)d_in[25];
  const float* Wo  = (const float*)d_in[26];
  const float* lnw = (const float*)d_in[27];
  const float* lnb = (const float*)d_in[28];
  float* outp = (float*)d_out;
  float* ws = (float*)d_ws;

  // workspace layout (floats)
  float* xk  = ws + 0;         // 4*512*512
  float* xv  = ws + 1048576;
  float* kgP = ws + 2097152;   // k raw, packed [b][h][tg][c][4]
  float* vpP = ws + 3145728;   // v_pre, packed
  float* svP = ws + 4194304;   // sigmoid lerp factor, packed
  float* kkP = ws + 5242880;   // normalized kk, packed
  float* Pw  = ws + 6291456;   // 4*512*32
  float* Pa  = ws + 6356992;
  float* Qw  = ws + 6422528;   // 32*32
  float* Qa  = ws + 6423552;
  float* HV  = ws + 6424576;   // 4*512*32
  float* rr  = ws + 7473152;   // 32*512
  float* gr  = ws + 7489536;
  float* xo  = ws + 7505920;
  float* wP  = ws + 7522304;   // 32*512*512 decay, packed [bq][h][tg][c][4]
  float* kP  = ws + 15910912;  // k_final, packed
  float* bP  = ws + 24299520;  // kk*a, packed
  float* xrw = ws + 32688128;  // 32*512
  float* ghw = ws + 32704512;  // 32*96

  // v_first passthrough (tuple output #2)
  hipMemcpyAsync(outp + BQ*CC, vf,
                 (size_t)BQ*TT*CC*sizeof(float), hipMemcpyDeviceToDevice, stream);

  k_prep<<<32, 256, 0, stream>>>(q, kv, x_r, x_w, x_a, x_g, w1, a1, g1,
                                 Qw, Qa, ghw, xrw);
  k_rg<<<dim3(8, 32), 256, 0, stream>>>(xrw, ghw, Wr, g2, rr, gr);
  k_shift<<<1024, 256, 0, stream>>>(kv, x_k, x_v, xk, xv);
  gemm2<<<dim3(8, 32, 2), 256, 0, stream>>>(xk, Wk, kgP, xv, Wv, vpP);
  k_pgemm<<<dim3(32, 3), 256, 0, stream>>>(kv, xv, x_w, x_a, w1, a1, v1,
                                           Pw, Pa, HV);
  k_svn<<<NB*TG, 512, 0, stream>>>(HV, v2, v0, k_k, kgP, svP, kkP);
  k_wkb<<<BQ*TG, 512, 0, stream>>>(Pw, Pa, Qw, Qa, w2, a2, w0, a0, k_a,
                                   kgP, kkP, wP, kP, bP);
  k_scan<<<BQ, 512, 0, stream>>>(wP, kP, bP, kkP, vpP, svP, vf, rr, gr, r_k,
                                 lnw, lnb, xo);
  k_out<<<dim3(8, 32), 256, 0, stream>>>(xo, Wo, outp);
}

// Round 10
// 357.262 us; speedup vs baseline: 1.1530x; 1.0873x over previous
//
#include <hip/hip_runtime.h>
#include <cstdint>

// Problem constants
#define TT 512   // KVLEN
#define CC 512   // C
#define HH 8     // heads
#define NN 64    // head dim
#define BQ 32    // BATCH*QLEN
#define NB 4     // BATCH
#define TG 128   // TT/4 packed groups

__device__ __forceinline__ float sigm(float x){ return 1.f/(1.f+__expf(-x)); }

__device__ __forceinline__ float wsum(float x){
  #pragma unroll
  for (int o=32;o;o>>=1) x += __shfl_xor(x, o, 64);
  return x;
}

// ---------------------------------------------------------------------------
// Batched wave64 row-sum, VALU-only: DPP row_ror tree + permlane16/32 swap.
// ---------------------------------------------------------------------------
template<int NR>
__device__ __forceinline__ void rowsum64_batch(float* x){
  #pragma unroll
  for (int i=0;i<NR;i++)
    x[i] += __int_as_float(__builtin_amdgcn_mov_dpp(__float_as_int(x[i]), 0x121, 0xf, 0xf, true));
  #pragma unroll
  for (int i=0;i<NR;i++)
    x[i] += __int_as_float(__builtin_amdgcn_mov_dpp(__float_as_int(x[i]), 0x122, 0xf, 0xf, true));
  #pragma unroll
  for (int i=0;i<NR;i++)
    x[i] += __int_as_float(__builtin_amdgcn_mov_dpp(__float_as_int(x[i]), 0x124, 0xf, 0xf, true));
  #pragma unroll
  for (int i=0;i<NR;i++)
    x[i] += __int_as_float(__builtin_amdgcn_mov_dpp(__float_as_int(x[i]), 0x128, 0xf, 0xf, true));
  float y[NR];
  #pragma unroll
  for (int i=0;i<NR;i++) asm("v_mov_b32 %0, %1" : "=v"(y[i]) : "v"(x[i]));
  #pragma unroll
  for (int i=0;i<NR;i++) asm("v_permlane16_swap_b32 %0, %1" : "+v"(x[i]), "+v"(y[i]));
  #pragma unroll
  for (int i=0;i<NR;i++) x[i] += y[i];
  #pragma unroll
  for (int i=0;i<NR;i++) asm("v_mov_b32 %0, %1" : "=v"(y[i]) : "v"(x[i]));
  #pragma unroll
  for (int i=0;i<NR;i++) asm("v_permlane32_swap_b32 %0, %1" : "+v"(x[i]), "+v"(y[i]));
  #pragma unroll
  for (int i=0;i<NR;i++) x[i] += y[i];
}

// ---------------------------------------------------------------------------
// k_prep: per-bq small dots (32 blocks): Qw[bq,32], Qa[bq,32], gh[bq,96],
// and xr row -> workspace.
// ---------------------------------------------------------------------------
__global__ __launch_bounds__(256) void k_prep(
  const float* __restrict__ q, const float* __restrict__ kv,
  const float* __restrict__ x_r, const float* __restrict__ x_w,
  const float* __restrict__ x_a, const float* __restrict__ x_g,
  const float* __restrict__ w1, const float* __restrict__ a1,
  const float* __restrict__ g1,
  float* __restrict__ Qw, float* __restrict__ Qa,
  float* __restrict__ ghw, float* __restrict__ xrw)
{
  int bq = blockIdx.x, b = bq >> 3, tid = threadIdx.x;
  int wave = tid >> 6, lane = tid & 63;
  __shared__ float qxw[CC], qxa[CC], sxg[CC];
  for (int c = tid; c < CC; c += 256){
    float qv = q[bq*CC + c];
    float kl = kv[((size_t)b*TT + (TT-1))*CC + c];
    xrw[bq*CC + c] = kl + (qv - kl)*x_r[c];
    sxg[c] = kl + (qv - kl)*x_g[c];
    qxw[c] = qv*x_w[c];
    qxa[c] = qv*x_a[c];
  }
  __syncthreads();
  for (int dot = wave; dot < 160; dot += 4){
    const float* buf; const float* W; int ld, dd;
    if (dot < 32)      { buf = qxw; W = w1; ld = 32; dd = dot; }
    else if (dot < 64) { buf = qxa; W = a1; ld = 32; dd = dot-32; }
    else               { buf = sxg; W = g1; ld = 96; dd = dot-64; }
    float s = 0.f;
    #pragma unroll
    for (int m = 0; m < 8; m++){
      int c = m*64 + lane;
      s = fmaf(buf[c], W[c*ld + dd], s);
    }
    s = wsum(s);
    if (lane == 0){
      if (dot < 32)      Qw[bq*32 + dd] = s;
      else if (dot < 64) Qa[bq*32 + dd] = s;
      else               ghw[bq*96 + dd] = sigm(s);
    }
  }
}

// ---------------------------------------------------------------------------
// k_rg: rrow[bq,co] = xr[bq,:]@Wr[:,co], grow[bq,co] = gh[bq,:]@g2[:,co]
// ---------------------------------------------------------------------------
__global__ __launch_bounds__(256) void k_rg(
  const float* __restrict__ xrw, const float* __restrict__ ghw,
  const float* __restrict__ Wr, const float* __restrict__ g2,
  float* __restrict__ rrow, float* __restrict__ grow)
{
  int bq = blockIdx.y; int co0 = blockIdx.x*64;
  int tid = threadIdx.x, tx = tid & 63, ty = tid >> 6;
  __shared__ float sxr[CC];
  __shared__ float sgh[96];
  __shared__ float red[4][64];
  sxr[tid]     = xrw[bq*CC + tid];
  sxr[tid+256] = xrw[bq*CC + tid + 256];
  if (tid < 96) sgh[tid] = ghw[bq*96 + tid];
  __syncthreads();
  float p = 0.f;
  for (int i = 0; i < 128; i++){
    int c = ty*128 + i;
    p = fmaf(sxr[c], Wr[(size_t)c*CC + co0 + tx], p);
  }
  red[ty][tx] = p;
  float pg = 0.f;
  for (int d = ty*24; d < ty*24 + 24; d++)
    pg = fmaf(sgh[d], g2[(size_t)d*CC + co0 + tx], pg);
  __syncthreads();
  if (ty == 0)
    rrow[bq*CC + co0 + tx] = (red[0][tx]+red[1][tx])+(red[2][tx]+red[3][tx]);
  __syncthreads();
  red[ty][tx] = pg;
  __syncthreads();
  if (ty == 0)
    grow[bq*CC + co0 + tx] = (red[0][tx]+red[1][tx])+(red[2][tx]+red[3][tx]);
}

// ---------------------------------------------------------------------------
// k_shift: elementwise token-shift mix: xk, xv.  float4, coalesced.
// ---------------------------------------------------------------------------
__global__ __launch_bounds__(256) void k_shift(
  const float* __restrict__ kv, const float* __restrict__ x_k,
  const float* __restrict__ x_v,
  float* __restrict__ xk, float* __restrict__ xv)
{
  int g = blockIdx.x*256 + threadIdx.x;      // float4 index, [0, 262144)
  int bt = g >> 7, t = bt & (TT-1), c4 = g & 127;
  const float4* kv4 = (const float4*)kv;
  float4 cur = kv4[g];
  float4 sh  = t ? kv4[g-128] : make_float4(0.f,0.f,0.f,0.f);
  float4 kc  = ((const float4*)x_k)[c4];
  float4 vc  = ((const float4*)x_v)[c4];
  float4 ok, ov;
  ok.x = cur.x + (sh.x-cur.x)*kc.x; ov.x = cur.x + (sh.x-cur.x)*vc.x;
  ok.y = cur.y + (sh.y-cur.y)*kc.y; ov.y = cur.y + (sh.y-cur.y)*vc.y;
  ok.z = cur.z + (sh.z-cur.z)*kc.z; ov.z = cur.z + (sh.z-cur.z)*vc.z;
  ok.w = cur.w + (sh.w-cur.w)*kc.w; ov.w = cur.w + (sh.w-cur.w)*vc.w;
  ((float4*)xk)[g] = ok;
  ((float4*)xv)[g] = ov;
}

// ---------------------------------------------------------------------------
// k_pgemm: three [2048x512]@[512x32] products (Pw, Pa, HV), tiled.
// ---------------------------------------------------------------------------
__global__ __launch_bounds__(256) void k_pgemm(
  const float* __restrict__ kv, const float* __restrict__ xv,
  const float* __restrict__ x_w, const float* __restrict__ x_a,
  const float* __restrict__ w1, const float* __restrict__ a1,
  const float* __restrict__ v1,
  float* __restrict__ Pw, float* __restrict__ Pa, float* __restrict__ HV)
{
  int mat = blockIdx.y;
  int r0 = blockIdx.x * 64;
  const float* A = (mat == 2) ? xv : kv;
  const float* B = (mat == 0) ? w1 : (mat == 1) ? a1 : v1;
  float* O       = (mat == 0) ? Pw : (mat == 1) ? Pa : HV;
  int tid = threadIdx.x;
  __shared__ float As[32][65];
  __shared__ float Bs[32][32];
  __shared__ float scl[CC];
  for (int c = tid; c < CC; c += 256)
    scl[c] = (mat == 0) ? (1.f - x_w[c]) : (mat == 1) ? (1.f - x_a[c]) : 1.f;
  __syncthreads();
  int tx = tid & 31, ty = tid >> 5;
  float acc[8];
  #pragma unroll
  for (int i = 0; i < 8; i++) acc[i] = 0.f;
  for (int k0 = 0; k0 < 512; k0 += 32){
    #pragma unroll
    for (int p = 0; p < 8; p++){
      int e = tid + p*256;
      int kk2 = e & 31, r = e >> 5;
      As[kk2][r] = A[(size_t)(r0+r)*512 + k0 + kk2] * scl[k0 + kk2];
    }
    #pragma unroll
    for (int p = 0; p < 4; p++){
      int e = tid + p*256;
      int n = e & 31, kk2 = e >> 5;
      Bs[kk2][n] = B[(size_t)(k0+kk2)*32 + n];
    }
    __syncthreads();
    #pragma unroll
    for (int kk2 = 0; kk2 < 32; kk2++){
      float bb = Bs[kk2][tx];
      #pragma unroll
      for (int i = 0; i < 8; i++)
        acc[i] = fmaf(As[kk2][ty*8 + i], bb, acc[i]);
    }
    __syncthreads();
  }
  #pragma unroll
  for (int i = 0; i < 8; i++)
    O[(size_t)(r0 + ty*8 + i)*32 + tx] = acc[i];
}

// ---------------------------------------------------------------------------
// gemm2: two [2048x512]@[512x512] in one dispatch (blockIdx.z).
// BOTH outputs packed [b][h][tg][c][4]: z=0 -> kgP (from xk@Wk),
// z=1 -> vpP (from xv@Wv).
// ---------------------------------------------------------------------------
__global__ __launch_bounds__(256) void gemm2(
  const float* __restrict__ A0, const float* __restrict__ W0, float* __restrict__ kgP,
  const float* __restrict__ A1, const float* __restrict__ W1, float* __restrict__ vpP)
{
  __shared__ float As[32][68];
  __shared__ float Bs[32][64];
  int z = blockIdx.z;
  const float* A = z ? A1 : A0;
  const float* W = z ? W1 : W0;
  int tid = threadIdx.x;
  int tx = tid & 15, ty = tid >> 4;
  int m0 = blockIdx.y*64, n0 = blockIdx.x*64;
  float acc[4][4];
  #pragma unroll
  for (int i=0;i<4;i++)
    #pragma unroll
    for (int j=0;j<4;j++) acc[i][j]=0.f;

  for (int k0 = 0; k0 < 512; k0 += 32){
    #pragma unroll
    for (int i = 0; i < 8; i++){
      int e = tid + i*256;
      int kk = e & 31, m = e >> 5;
      As[kk][m] = A[(size_t)(m0+m)*512 + k0 + kk];
    }
    #pragma unroll
    for (int i = 0; i < 8; i++){
      int e = tid + i*256;
      int n = e & 63, kk = e >> 6;
      Bs[kk][n] = W[(size_t)(k0+kk)*512 + n0 + n];
    }
    __syncthreads();
    #pragma unroll
    for (int kk = 0; kk < 32; kk++){
      float a4[4], b4[4];
      #pragma unroll
      for (int i=0;i<4;i++) a4[i] = As[kk][ty*4+i];
      #pragma unroll
      for (int j=0;j<4;j++) b4[j] = Bs[kk][tx*4+j];
      #pragma unroll
      for (int i=0;i<4;i++)
        #pragma unroll
        for (int j=0;j<4;j++) acc[i][j] += a4[i]*b4[j];
    }
    __syncthreads();
  }
  // packed store: rows m..m+3 are 4 consecutive t (u=0..3)
  int m = m0 + ty*4;
  int b = m >> 9, t = m & (TT-1), tg = t >> 2;
  int h = n0 >> 6;
  float* dstB = z ? vpP : kgP;
  float4* dst = (float4*)dstB + ((size_t)(b*HH + h)*TG + tg)*64 + tx*4;
  #pragma unroll
  for (int j=0;j<4;j++)
    dst[j] = make_float4(acc[0][j],acc[1][j],acc[2][j],acc[3][j]);
}

// ---------------------------------------------------------------------------
// k_svn: fused kk-normalize + sv.  Per (b,tg), 512 threads (one channel).
// kk = normalize_per_head(kgP*k_k) via rowsum64_batch<4>; sv = sigm(v0+HV@v2).
// Writes kkP, svP packed.
// ---------------------------------------------------------------------------
__global__ __launch_bounds__(512) void k_svn(
  const float* __restrict__ HV, const float* __restrict__ v2,
  const float* __restrict__ v0, const float* __restrict__ k_k,
  const float* __restrict__ kgP,
  float* __restrict__ svP, float* __restrict__ kkP)
{
  int blk = blockIdx.x;            // b*TG + tg
  int b = blk >> 7, tg = blk & (TG-1);
  int tid = threadIdx.x;           // channel c
  __shared__ float hv[4][32];
  if (tid < 128){
    int u = tid >> 5, d = tid & 31;
    hv[u][d] = HV[((size_t)(b*TT + tg*4 + u))*32 + d];
  }
  __syncthreads();
  int c = tid, h = c >> 6, cc0 = c & 63;
  size_t o = ((size_t)(b*HH + h)*TG + tg)*64 + cc0;
  float4 kg4 = ((const float4*)kgP)[o];
  float kkc = k_k[c];
  float q0 = kg4.x*kkc, q1 = kg4.y*kkc, q2 = kg4.z*kkc, q3 = kg4.w*kkc;
  float ss[4] = {q0*q0, q1*q1, q2*q2, q3*q3};
  rowsum64_batch<4>(ss);            // per-wave = per-head sum
  float4 kkq;
  kkq.x = q0 / fmaxf(sqrtf(ss[0]), 1e-12f);
  kkq.y = q1 / fmaxf(sqrtf(ss[1]), 1e-12f);
  kkq.z = q2 / fmaxf(sqrtf(ss[2]), 1e-12f);
  kkq.w = q3 / fmaxf(sqrtf(ss[3]), 1e-12f);
  ((float4*)kkP)[o] = kkq;
  float v0c = v0[c];
  float s0 = v0c, s1 = v0c, s2 = v0c, s3 = v0c;
  #pragma unroll
  for (int d = 0; d < 32; d++){
    float vc = v2[d*CC + c];
    s0 = fmaf(hv[0][d], vc, s0);
    s1 = fmaf(hv[1][d], vc, s1);
    s2 = fmaf(hv[2][d], vc, s2);
    s3 = fmaf(hv[3][d], vc, s3);
  }
  ((float4*)svP)[o] = make_float4(sigm(s0), sigm(s1), sigm(s2), sigm(s3));
}

// ---------------------------------------------------------------------------
// k_wkb: per (bq,t,c): decay w, k_final, b_vec = kk*a.  R5-proven structure
// (512 threads, one channel each, register-cached w2/a2 columns), kg/kk
// reads packed float4.
// ---------------------------------------------------------------------------
__global__ __launch_bounds__(512) void k_wkb(
  const float* __restrict__ Pw, const float* __restrict__ Pa,
  const float* __restrict__ Qw, const float* __restrict__ Qa,
  const float* __restrict__ w2, const float* __restrict__ a2,
  const float* __restrict__ w0, const float* __restrict__ a0,
  const float* __restrict__ k_a,
  const float* __restrict__ kgP, const float* __restrict__ kkP,
  float* __restrict__ wP, float* __restrict__ kP, float* __restrict__ bP)
{
  int blk = blockIdx.x;              // bq*TG + tg
  int bq = blk >> 7, tg = blk & (TG-1), t0 = tg*4, b = bq >> 3;
  int tid = threadIdx.x;             // = channel c, 0..511
  __shared__ float sth[4][32], sal[4][32];
  if (tid < 256){
    int g = (tid >> 5) & 3, d = tid & 31;
    int pidx = ((b << 9) | (t0 + g))*32 + d;
    if (tid < 128) sth[g][d] = tanhf(Pw[pidx] + Qw[bq*32 + d]);
    else           sal[g][d] = Pa[pidx] + Qa[bq*32 + d];
  }
  __syncthreads();
  int c = tid, h = c >> 6, cc0 = c & 63;
  float wreg[32], areg[32];
  #pragma unroll
  for (int d = 0; d < 32; d++){ wreg[d] = w2[d*CC + c]; areg[d] = a2[d*CC + c]; }
  float w0c = w0[c], a0c = a0[c], kac = k_a[c];
  size_t ob = ((size_t)(b*HH + h)*TG + tg)*64 + cc0;
  float4 kg4 = ((const float4*)kgP)[ob];
  float4 kk4 = ((const float4*)kkP)[ob];
  float kga[4] = {kg4.x, kg4.y, kg4.z, kg4.w};
  float kka[4] = {kk4.x, kk4.y, kk4.z, kk4.w};
  float w4a[4], k4a[4], b4a[4];
  #pragma unroll
  for (int g = 0; g < 4; g++){
    float wa = 0.f, aa = 0.f;
    #pragma unroll
    for (int d = 0; d < 32; d++){
      wa = fmaf(sth[g][d], wreg[d], wa);
      aa = fmaf(sal[g][d], areg[d], aa);
    }
    float a_sig = sigm(a0c + aa);
    w4a[g] = __expf(-0.60653066f * sigm(w0c + wa));
    k4a[g] = kga[g]*(1.f + (a_sig - 1.f)*kac);
    b4a[g] = kka[g]*a_sig;
  }
  size_t o = ((size_t)(bq*HH + h)*TG + tg)*64 + cc0;
  ((float4*)wP)[o] = make_float4(w4a[0],w4a[1],w4a[2],w4a[3]);
  ((float4*)kP)[o] = make_float4(k4a[0],k4a[1],k4a[2],k4a[3]);
  ((float4*)bP)[o] = make_float4(b4a[0],b4a[1],b4a[2],b4a[3]);
}

// ---------------------------------------------------------------------------
// K3: BACKWARD vector scan — R5-measured geometry (256 blocks x 64 thr,
// 52us floor; R6/R7/R9 all failed to beat the 244cy/step serial chain).
// R10: the v_first PASSTHROUGH is fused here — k_scan already reads every
// vfirst element exactly once (grid covers all bq x t x channel), so it
// stores each prefetched value to the output buffer and the 45-55us
// hipMemcpyAsync (134MB r + 134MB w, serialized in-stream) is deleted.
// Stores are fire-and-forget 256B-coalesced, ~2 inst/step.
// ---------------------------------------------------------------------------
#define SCAN_STEP(wc,kc,bc,ac,pc,sc,vfc) do{ \
  float vj = fmaf((vfc)-(pc), (sc), (pc)); \
  float rr[2]; rr[0]=(kc)*g; rr[1]=(bc)*g; \
  rowsum64_batch<2>(rr); \
  out = fmaf(rr[0], vj, out); \
  g = fmaf((wc), g, -((ac)*rr[1])); }while(0)

__global__ __launch_bounds__(64, 1) void k_scan(
  const float* __restrict__ wP, const float* __restrict__ kP,
  const float* __restrict__ bP, const float* __restrict__ kkP,
  const float* __restrict__ vpP, const float* __restrict__ svP,
  const float* __restrict__ vfirst,
  const float* __restrict__ rrow, const float* __restrict__ grow,
  const float* __restrict__ r_k, const float* __restrict__ ln_w,
  const float* __restrict__ ln_b, float* __restrict__ xo,
  float* __restrict__ vf_out)
{
  int blk = blockIdx.x; int bq = blk >> 3, h = blk & 7, b = bq >> 3;
  int lane = threadIdx.x & 63;

  // per-(bq,h) packed bases: TG*64 float4s each
  const float4* wp4 = (const float4*)wP  + ((size_t)(bq*HH + h))*TG*64 + lane;
  const float4* kp4 = (const float4*)kP  + ((size_t)(bq*HH + h))*TG*64 + lane;
  const float4* bp4 = (const float4*)bP  + ((size_t)(bq*HH + h))*TG*64 + lane;
  const float4* ap4 = (const float4*)kkP + ((size_t)(b*HH + h))*TG*64 + lane;
  const float4* pp4 = (const float4*)vpP + ((size_t)(b*HH + h))*TG*64 + lane;
  const float4* sp4 = (const float4*)svP + ((size_t)(b*HH + h))*TG*64 + lane;
  const float*  pvf = vfirst + (size_t)bq*TT*CC + h*NN + lane;
  float*        pvo = vf_out + (size_t)bq*TT*CC + h*NN + lane;

  float g   = rrow[(size_t)bq*CC + h*NN + lane];   // g_{T-1} = r
  float out = 0.f;

  constexpr int PD = 4;                // prefetch depth, in groups of 4 steps
  float4 fw[PD], fk[PD], fb[PD], fa[PD], fp[PD], fs[PD];
  float fv0[PD], fv1[PD], fv2[PD], fv3[PD];
  #pragma unroll
  for (int d = 0; d < PD; ++d){
    int gg = TG-1 - d; int go = gg*64;
    fw[d]=wp4[go]; fk[d]=kp4[go]; fb[d]=bp4[go]; fa[d]=ap4[go];
    fp[d]=pp4[go]; fs[d]=sp4[go];
    const float* pv = pvf + (size_t)(4*gg)*CC;
    fv0[d]=pv[0]; fv1[d]=pv[CC]; fv2[d]=pv[2*CC]; fv3[d]=pv[3*CC];
  }

  #pragma unroll 1
  for (int gb = 0; gb < TG; gb += PD){
    #pragma unroll
    for (int sl = 0; sl < PD; ++sl){
      int gi = TG-1 - (gb + sl);       // current group (descending)
      // snapshot slot
      float4 w4=fw[sl], k4=fk[sl], b4=fb[sl], a4=fa[sl], p4=fp[sl], s4=fs[sl];
      float v3=fv3[sl], v2_=fv2[sl], v1_=fv1[sl], v0_=fv0[sl];
      // v_first passthrough: store this group's 4 values (read exactly once
      // across the grid -> replaces the 134MB hipMemcpyAsync)
      {
        float* po = pvo + (size_t)(4*gi)*CC;
        po[0] = v0_; po[CC] = v1_; po[2*CC] = v2_; po[3*CC] = v3;
      }
      // prefetch group gi-PD into slot sl (clamped; dup loads harmless)
      int gp = gi - PD; gp = gp < 0 ? 0 : gp; int go = gp*64;
      fw[sl]=wp4[go]; fk[sl]=kp4[go]; fb[sl]=bp4[go]; fa[sl]=ap4[go];
      fp[sl]=pp4[go]; fs[sl]=sp4[go];
      { const float* pv = pvf + (size_t)(4*gp)*CC;
        fv0[sl]=pv[0]; fv1[sl]=pv[CC]; fv2[sl]=pv[2*CC]; fv3[sl]=pv[3*CC]; }
      __builtin_amdgcn_sched_barrier(0);   // pin loads in this iteration
      // 4 steps, s = 4*gi+3 .. 4*gi+0
      SCAN_STEP(w4.w,k4.w,b4.w,a4.w,p4.w,s4.w,v3);
      SCAN_STEP(w4.z,k4.z,b4.z,a4.z,p4.z,s4.z,v2_);
      SCAN_STEP(w4.y,k4.y,b4.y,a4.y,p4.y,s4.y,v1_);
      SCAN_STEP(w4.x,k4.x,b4.x,a4.x,p4.x,s4.x,v0_);
    }
  }

  // epilogue: groupnorm over head + rk*v term + gate (per-lane channel)
  {
    float mean = wsum(out) * (1.f/NN);
    float dv = out - mean;
    float var = wsum(dv*dv) * (1.f/NN);
    float yn = dv * rsqrtf(var + 6.4e-4f);   // GN_EPS = 1e-5*64
    int c = h*NN + lane;
    float y2 = yn * ln_w[c] + ln_b[c];
    int goT = (TG-1)*64;
    float kl  = kp4[goT].w;                  // k at t = T-1
    float rl  = rrow[(size_t)bq*CC + c];
    float rk  = wsum(rl*kl*r_k[c]);
    float vp_ = pp4[goT].w, sv_ = sp4[goT].w;
    float vf_ = pvf[(size_t)(TT-1)*CC];
    float v_i = fmaf(vf_ - vp_, sv_, vp_);   // v_{T-1}
    float res = (y2 + rk*v_i) * grow[(size_t)bq*CC + c];
    xo[bq*CC + c] = res;
  }
}

// ---------------------------------------------------------------------------
// K4: out[bq,co] = xo[bq,:] @ Wo[:,co]
// ---------------------------------------------------------------------------
__global__ __launch_bounds__(256) void k_out(
  const float* __restrict__ xo, const float* __restrict__ Wo,
  float* __restrict__ outp)
{
  int bq = blockIdx.y; int co0 = blockIdx.x*64;
  int tid = threadIdx.x, tx = tid & 63, ty = tid >> 6;
  __shared__ float row[CC];
  __shared__ float red[4][64];
  row[tid]     = xo[bq*CC + tid];
  row[tid+256] = xo[bq*CC + tid + 256];
  __syncthreads();
  float p = 0.f;
  for (int i = 0; i < 128; i++){
    int c = ty*128 + i;
    p = fmaf(row[c], Wo[(size_t)c*CC + co0 + tx], p);
  }
  red[ty][tx] = p;
  __syncthreads();
  if (ty == 0)
    outp[bq*CC + co0 + tx] = (red[0][tx]+red[1][tx])+(red[2][tx]+red[3][tx]);
}

// ---------------------------------------------------------------------------
extern "C" void kernel_launch(void* const* d_in, const int* in_sizes, int n_in,
                              void* d_out, int out_size, void* d_ws, size_t ws_size,
                              hipStream_t stream)
{
  const float* q   = (const float*)d_in[0];
  const float* kv  = (const float*)d_in[1];
  const float* vf  = (const float*)d_in[2];
  const float* x_r = (const float*)d_in[3];
  const float* x_w = (const float*)d_in[4];
  const float* x_k = (const float*)d_in[5];
  const float* x_v = (const float*)d_in[6];
  const float* x_a = (const float*)d_in[7];
  const float* x_g = (const float*)d_in[8];
  const float* w0  = (const float*)d_in[9];
  const float* w1  = (const float*)d_in[10];
  const float* w2  = (const float*)d_in[11];
  const float* a0  = (const float*)d_in[12];
  const float* a1  = (const float*)d_in[13];
  const float* a2  = (const float*)d_in[14];
  const float* v0  = (const float*)d_in[15];
  const float* v1  = (const float*)d_in[16];
  const float* v2  = (const float*)d_in[17];
  const float* g1  = (const float*)d_in[18];
  const float* g2  = (const float*)d_in[19];
  const float* k_k = (const float*)d_in[20];
  const float* k_a = (const float*)d_in[21];
  const float* r_k = (const float*)d_in[22];
  const float* Wr  = (const float*)d_in[23];
  const float* Wk  = (const float*)d_in[24];
  const float* Wv  = (const float*)d_in[25];
  const float* Wo  = (const float*)d_in[26];
  const float* lnw = (const float*)d_in[27];
  const float* lnb = (const float*)d_in[28];
  float* outp = (float*)d_out;
  float* ws = (float*)d_ws;

  // workspace layout (floats)
  float* xk  = ws + 0;         // 4*512*512
  float* xv  = ws + 1048576;
  float* kgP = ws + 2097152;   // k raw, packed [b][h][tg][c][4]
  float* vpP = ws + 3145728;   // v_pre, packed
  float* svP = ws + 4194304;   // sigmoid lerp factor, packed
  float* kkP = ws + 5242880;   // normalized kk, packed
  float* Pw  = ws + 6291456;   // 4*512*32
  float* Pa  = ws + 6356992;
  float* Qw  = ws + 6422528;   // 32*32
  float* Qa  = ws + 6423552;
  float* HV  = ws + 6424576;   // 4*512*32
  float* rr  = ws + 7473152;   // 32*512
  float* gr  = ws + 7489536;
  float* xo  = ws + 7505920;
  float* wP  = ws + 7522304;   // 32*512*512 decay, packed [bq][h][tg][c][4]
  float* kP  = ws + 15910912;  // k_final, packed
  float* bP  = ws + 24299520;  // kk*a, packed
  float* xrw = ws + 32688128;  // 32*512
  float* ghw = ws + 32704512;  // 32*96

  k_prep<<<32, 256, 0, stream>>>(q, kv, x_r, x_w, x_a, x_g, w1, a1, g1,
                                 Qw, Qa, ghw, xrw);
  k_rg<<<dim3(8, 32), 256, 0, stream>>>(xrw, ghw, Wr, g2, rr, gr);
  k_shift<<<1024, 256, 0, stream>>>(kv, x_k, x_v, xk, xv);
  gemm2<<<dim3(8, 32, 2), 256, 0, stream>>>(xk, Wk, kgP, xv, Wv, vpP);
  k_pgemm<<<dim3(32, 3), 256, 0, stream>>>(kv, xv, x_w, x_a, w1, a1, v1,
                                           Pw, Pa, HV);
  k_svn<<<NB*TG, 512, 0, stream>>>(HV, v2, v0, k_k, kgP, svP, kkP);
  k_wkb<<<BQ*TG, 512, 0, stream>>>(Pw, Pa, Qw, Qa, w2, a2, w0, a0, k_a,
                                   kgP, kkP, wP, kP, bP);
  k_scan<<<BQ*HH, 64, 0, stream>>>(wP, kP, bP, kkP, vpP, svP, vf, rr, gr, r_k,
                                   lnw, lnb, xo, outp + BQ*CC);
  k_out<<<dim3(8, 32), 256, 0, stream>>>(xo, Wo, outp);
}

// Round 11
// 347.906 us; speedup vs baseline: 1.1840x; 1.0269x over previous
//
#include <hip/hip_runtime.h>
#include <cstdint>

// Problem constants
#define TT 512   // KVLEN
#define CC 512   // C
#define HH 8     // heads
#define NN 64    // head dim
#define BQ 32    // BATCH*QLEN
#define NB 4     // BATCH
#define TG 128   // TT/4 packed groups

__device__ __forceinline__ float sigm(float x){ return 1.f/(1.f+__expf(-x)); }

__device__ __forceinline__ float wsum(float x){
  #pragma unroll
  for (int o=32;o;o>>=1) x += __shfl_xor(x, o, 64);
  return x;
}

// ---------------------------------------------------------------------------
// Batched wave64 row-sum, VALU-only: DPP row_ror tree + permlane16/32 swap.
// ---------------------------------------------------------------------------
template<int NR>
__device__ __forceinline__ void rowsum64_batch(float* x){
  #pragma unroll
  for (int i=0;i<NR;i++)
    x[i] += __int_as_float(__builtin_amdgcn_mov_dpp(__float_as_int(x[i]), 0x121, 0xf, 0xf, true));
  #pragma unroll
  for (int i=0;i<NR;i++)
    x[i] += __int_as_float(__builtin_amdgcn_mov_dpp(__float_as_int(x[i]), 0x122, 0xf, 0xf, true));
  #pragma unroll
  for (int i=0;i<NR;i++)
    x[i] += __int_as_float(__builtin_amdgcn_mov_dpp(__float_as_int(x[i]), 0x124, 0xf, 0xf, true));
  #pragma unroll
  for (int i=0;i<NR;i++)
    x[i] += __int_as_float(__builtin_amdgcn_mov_dpp(__float_as_int(x[i]), 0x128, 0xf, 0xf, true));
  float y[NR];
  #pragma unroll
  for (int i=0;i<NR;i++) asm("v_mov_b32 %0, %1" : "=v"(y[i]) : "v"(x[i]));
  #pragma unroll
  for (int i=0;i<NR;i++) asm("v_permlane16_swap_b32 %0, %1" : "+v"(x[i]), "+v"(y[i]));
  #pragma unroll
  for (int i=0;i<NR;i++) x[i] += y[i];
  #pragma unroll
  for (int i=0;i<NR;i++) asm("v_mov_b32 %0, %1" : "=v"(y[i]) : "v"(x[i]));
  #pragma unroll
  for (int i=0;i<NR;i++) asm("v_permlane32_swap_b32 %0, %1" : "+v"(x[i]), "+v"(y[i]));
  #pragma unroll
  for (int i=0;i<NR;i++) x[i] += y[i];
}

// ---------------------------------------------------------------------------
// k_prep: per-bq small dots (32 blocks): Qw[bq,32], Qa[bq,32], gh[bq,96],
// and xr row -> workspace.
// ---------------------------------------------------------------------------
__global__ __launch_bounds__(256) void k_prep(
  const float* __restrict__ q, const float* __restrict__ kv,
  const float* __restrict__ x_r, const float* __restrict__ x_w,
  const float* __restrict__ x_a, const float* __restrict__ x_g,
  const float* __restrict__ w1, const float* __restrict__ a1,
  const float* __restrict__ g1,
  float* __restrict__ Qw, float* __restrict__ Qa,
  float* __restrict__ ghw, float* __restrict__ xrw)
{
  int bq = blockIdx.x, b = bq >> 3, tid = threadIdx.x;
  int wave = tid >> 6, lane = tid & 63;
  __shared__ float qxw[CC], qxa[CC], sxg[CC];
  for (int c = tid; c < CC; c += 256){
    float qv = q[bq*CC + c];
    float kl = kv[((size_t)b*TT + (TT-1))*CC + c];
    xrw[bq*CC + c] = kl + (qv - kl)*x_r[c];
    sxg[c] = kl + (qv - kl)*x_g[c];
    qxw[c] = qv*x_w[c];
    qxa[c] = qv*x_a[c];
  }
  __syncthreads();
  for (int dot = wave; dot < 160; dot += 4){
    const float* buf; const float* W; int ld, dd;
    if (dot < 32)      { buf = qxw; W = w1; ld = 32; dd = dot; }
    else if (dot < 64) { buf = qxa; W = a1; ld = 32; dd = dot-32; }
    else               { buf = sxg; W = g1; ld = 96; dd = dot-64; }
    float s = 0.f;
    #pragma unroll
    for (int m = 0; m < 8; m++){
      int c = m*64 + lane;
      s = fmaf(buf[c], W[c*ld + dd], s);
    }
    s = wsum(s);
    if (lane == 0){
      if (dot < 32)      Qw[bq*32 + dd] = s;
      else if (dot < 64) Qa[bq*32 + dd] = s;
      else               ghw[bq*96 + dd] = sigm(s);
    }
  }
}

// ---------------------------------------------------------------------------
// k_rg: rrow[bq,co] = xr[bq,:]@Wr[:,co], grow[bq,co] = gh[bq,:]@g2[:,co]
// ---------------------------------------------------------------------------
__global__ __launch_bounds__(256) void k_rg(
  const float* __restrict__ xrw, const float* __restrict__ ghw,
  const float* __restrict__ Wr, const float* __restrict__ g2,
  float* __restrict__ rrow, float* __restrict__ grow)
{
  int bq = blockIdx.y; int co0 = blockIdx.x*64;
  int tid = threadIdx.x, tx = tid & 63, ty = tid >> 6;
  __shared__ float sxr[CC];
  __shared__ float sgh[96];
  __shared__ float red[4][64];
  sxr[tid]     = xrw[bq*CC + tid];
  sxr[tid+256] = xrw[bq*CC + tid + 256];
  if (tid < 96) sgh[tid] = ghw[bq*96 + tid];
  __syncthreads();
  float p = 0.f;
  for (int i = 0; i < 128; i++){
    int c = ty*128 + i;
    p = fmaf(sxr[c], Wr[(size_t)c*CC + co0 + tx], p);
  }
  red[ty][tx] = p;
  float pg = 0.f;
  for (int d = ty*24; d < ty*24 + 24; d++)
    pg = fmaf(sgh[d], g2[(size_t)d*CC + co0 + tx], pg);
  __syncthreads();
  if (ty == 0)
    rrow[bq*CC + co0 + tx] = (red[0][tx]+red[1][tx])+(red[2][tx]+red[3][tx]);
  __syncthreads();
  red[ty][tx] = pg;
  __syncthreads();
  if (ty == 0)
    grow[bq*CC + co0 + tx] = (red[0][tx]+red[1][tx])+(red[2][tx]+red[3][tx]);
}

// ---------------------------------------------------------------------------
// k_shift: elementwise token-shift mix: xk, xv.  float4, coalesced.
// ---------------------------------------------------------------------------
__global__ __launch_bounds__(256) void k_shift(
  const float* __restrict__ kv, const float* __restrict__ x_k,
  const float* __restrict__ x_v,
  float* __restrict__ xk, float* __restrict__ xv)
{
  int g = blockIdx.x*256 + threadIdx.x;      // float4 index, [0, 262144)
  int bt = g >> 7, t = bt & (TT-1), c4 = g & 127;
  const float4* kv4 = (const float4*)kv;
  float4 cur = kv4[g];
  float4 sh  = t ? kv4[g-128] : make_float4(0.f,0.f,0.f,0.f);
  float4 kc  = ((const float4*)x_k)[c4];
  float4 vc  = ((const float4*)x_v)[c4];
  float4 ok, ov;
  ok.x = cur.x + (sh.x-cur.x)*kc.x; ov.x = cur.x + (sh.x-cur.x)*vc.x;
  ok.y = cur.y + (sh.y-cur.y)*kc.y; ov.y = cur.y + (sh.y-cur.y)*vc.y;
  ok.z = cur.z + (sh.z-cur.z)*kc.z; ov.z = cur.z + (sh.z-cur.z)*vc.z;
  ok.w = cur.w + (sh.w-cur.w)*kc.w; ov.w = cur.w + (sh.w-cur.w)*vc.w;
  ((float4*)xk)[g] = ok;
  ((float4*)xv)[g] = ov;
}

// ---------------------------------------------------------------------------
// k_pgemm: three [2048x512]@[512x32] products (Pw, Pa, HV), tiled.
// ---------------------------------------------------------------------------
__global__ __launch_bounds__(256) void k_pgemm(
  const float* __restrict__ kv, const float* __restrict__ xv,
  const float* __restrict__ x_w, const float* __restrict__ x_a,
  const float* __restrict__ w1, const float* __restrict__ a1,
  const float* __restrict__ v1,
  float* __restrict__ Pw, float* __restrict__ Pa, float* __restrict__ HV)
{
  int mat = blockIdx.y;
  int r0 = blockIdx.x * 64;
  const float* A = (mat == 2) ? xv : kv;
  const float* B = (mat == 0) ? w1 : (mat == 1) ? a1 : v1;
  float* O       = (mat == 0) ? Pw : (mat == 1) ? Pa : HV;
  int tid = threadIdx.x;
  __shared__ float As[32][65];
  __shared__ float Bs[32][32];
  __shared__ float scl[CC];
  for (int c = tid; c < CC; c += 256)
    scl[c] = (mat == 0) ? (1.f - x_w[c]) : (mat == 1) ? (1.f - x_a[c]) : 1.f;
  __syncthreads();
  int tx = tid & 31, ty = tid >> 5;
  float acc[8];
  #pragma unroll
  for (int i = 0; i < 8; i++) acc[i] = 0.f;
  for (int k0 = 0; k0 < 512; k0 += 32){
    #pragma unroll
    for (int p = 0; p < 8; p++){
      int e = tid + p*256;
      int kk2 = e & 31, r = e >> 5;
      As[kk2][r] = A[(size_t)(r0+r)*512 + k0 + kk2] * scl[k0 + kk2];
    }
    #pragma unroll
    for (int p = 0; p < 4; p++){
      int e = tid + p*256;
      int n = e & 31, kk2 = e >> 5;
      Bs[kk2][n] = B[(size_t)(k0+kk2)*32 + n];
    }
    __syncthreads();
    #pragma unroll
    for (int kk2 = 0; kk2 < 32; kk2++){
      float bb = Bs[kk2][tx];
      #pragma unroll
      for (int i = 0; i < 8; i++)
        acc[i] = fmaf(As[kk2][ty*8 + i], bb, acc[i]);
    }
    __syncthreads();
  }
  #pragma unroll
  for (int i = 0; i < 8; i++)
    O[(size_t)(r0 + ty*8 + i)*32 + tx] = acc[i];
}

// ---------------------------------------------------------------------------
// gemm2: two [2048x512]@[512x512] in one dispatch (blockIdx.z).
// BOTH outputs packed [b][h][tg][c][4]: z=0 -> kgP (from xk@Wk),
// z=1 -> vpP (from xv@Wv).
// ---------------------------------------------------------------------------
__global__ __launch_bounds__(256) void gemm2(
  const float* __restrict__ A0, const float* __restrict__ W0, float* __restrict__ kgP,
  const float* __restrict__ A1, const float* __restrict__ W1, float* __restrict__ vpP)
{
  __shared__ float As[32][68];
  __shared__ float Bs[32][64];
  int z = blockIdx.z;
  const float* A = z ? A1 : A0;
  const float* W = z ? W1 : W0;
  int tid = threadIdx.x;
  int tx = tid & 15, ty = tid >> 4;
  int m0 = blockIdx.y*64, n0 = blockIdx.x*64;
  float acc[4][4];
  #pragma unroll
  for (int i=0;i<4;i++)
    #pragma unroll
    for (int j=0;j<4;j++) acc[i][j]=0.f;

  for (int k0 = 0; k0 < 512; k0 += 32){
    #pragma unroll
    for (int i = 0; i < 8; i++){
      int e = tid + i*256;
      int kk = e & 31, m = e >> 5;
      As[kk][m] = A[(size_t)(m0+m)*512 + k0 + kk];
    }
    #pragma unroll
    for (int i = 0; i < 8; i++){
      int e = tid + i*256;
      int n = e & 63, kk = e >> 6;
      Bs[kk][n] = W[(size_t)(k0+kk)*512 + n0 + n];
    }
    __syncthreads();
    #pragma unroll
    for (int kk = 0; kk < 32; kk++){
      float a4[4], b4[4];
      #pragma unroll
      for (int i=0;i<4;i++) a4[i] = As[kk][ty*4+i];
      #pragma unroll
      for (int j=0;j<4;j++) b4[j] = Bs[kk][tx*4+j];
      #pragma unroll
      for (int i=0;i<4;i++)
        #pragma unroll
        for (int j=0;j<4;j++) acc[i][j] += a4[i]*b4[j];
    }
    __syncthreads();
  }
  // packed store: rows m..m+3 are 4 consecutive t (u=0..3)
  int m = m0 + ty*4;
  int b = m >> 9, t = m & (TT-1), tg = t >> 2;
  int h = n0 >> 6;
  float* dstB = z ? vpP : kgP;
  float4* dst = (float4*)dstB + ((size_t)(b*HH + h)*TG + tg)*64 + tx*4;
  #pragma unroll
  for (int j=0;j<4;j++)
    dst[j] = make_float4(acc[0][j],acc[1][j],acc[2][j],acc[3][j]);
}

// ---------------------------------------------------------------------------
// k_svn: fused kk-normalize + sv.  Per (b,tg), 512 threads (one channel).
// kk = normalize_per_head(kgP*k_k) via rowsum64_batch<4>; sv = sigm(v0+HV@v2).
// Writes kkP, svP packed.
// ---------------------------------------------------------------------------
__global__ __launch_bounds__(512) void k_svn(
  const float* __restrict__ HV, const float* __restrict__ v2,
  const float* __restrict__ v0, const float* __restrict__ k_k,
  const float* __restrict__ kgP,
  float* __restrict__ svP, float* __restrict__ kkP)
{
  int blk = blockIdx.x;            // b*TG + tg
  int b = blk >> 7, tg = blk & (TG-1);
  int tid = threadIdx.x;           // channel c
  __shared__ float hv[4][32];
  if (tid < 128){
    int u = tid >> 5, d = tid & 31;
    hv[u][d] = HV[((size_t)(b*TT + tg*4 + u))*32 + d];
  }
  __syncthreads();
  int c = tid, h = c >> 6, cc0 = c & 63;
  size_t o = ((size_t)(b*HH + h)*TG + tg)*64 + cc0;
  float4 kg4 = ((const float4*)kgP)[o];
  float kkc = k_k[c];
  float q0 = kg4.x*kkc, q1 = kg4.y*kkc, q2 = kg4.z*kkc, q3 = kg4.w*kkc;
  float ss[4] = {q0*q0, q1*q1, q2*q2, q3*q3};
  rowsum64_batch<4>(ss);            // per-wave = per-head sum
  float4 kkq;
  kkq.x = q0 / fmaxf(sqrtf(ss[0]), 1e-12f);
  kkq.y = q1 / fmaxf(sqrtf(ss[1]), 1e-12f);
  kkq.z = q2 / fmaxf(sqrtf(ss[2]), 1e-12f);
  kkq.w = q3 / fmaxf(sqrtf(ss[3]), 1e-12f);
  ((float4*)kkP)[o] = kkq;
  float v0c = v0[c];
  float s0 = v0c, s1 = v0c, s2 = v0c, s3 = v0c;
  #pragma unroll
  for (int d = 0; d < 32; d++){
    float vc = v2[d*CC + c];
    s0 = fmaf(hv[0][d], vc, s0);
    s1 = fmaf(hv[1][d], vc, s1);
    s2 = fmaf(hv[2][d], vc, s2);
    s3 = fmaf(hv[3][d], vc, s3);
  }
  ((float4*)svP)[o] = make_float4(sigm(s0), sigm(s1), sigm(s2), sigm(s3));
}

// ---------------------------------------------------------------------------
// k_wa: per (bq,t,c): decay w and a_sig ONLY (k_final/b_vec computed
// in-flight by k_scan from kgP/kkP/aP).  R5-proven structure: 512 threads,
// one channel each, register-cached w2/a2 columns.  Writes 67MB instead of
// k_wkb's 100MB; drops its 33MB kgP/kkP reads.
// ---------------------------------------------------------------------------
__global__ __launch_bounds__(512) void k_wa(
  const float* __restrict__ Pw, const float* __restrict__ Pa,
  const float* __restrict__ Qw, const float* __restrict__ Qa,
  const float* __restrict__ w2, const float* __restrict__ a2,
  const float* __restrict__ w0, const float* __restrict__ a0,
  float* __restrict__ wP, float* __restrict__ aP)
{
  int blk = blockIdx.x;              // bq*TG + tg
  int bq = blk >> 7, tg = blk & (TG-1), t0 = tg*4, b = bq >> 3;
  int tid = threadIdx.x;             // = channel c, 0..511
  __shared__ float sth[4][32], sal[4][32];
  if (tid < 256){
    int g = (tid >> 5) & 3, d = tid & 31;
    int pidx = ((b << 9) | (t0 + g))*32 + d;
    if (tid < 128) sth[g][d] = tanhf(Pw[pidx] + Qw[bq*32 + d]);
    else           sal[g][d] = Pa[pidx] + Qa[bq*32 + d];
  }
  __syncthreads();
  int c = tid, h = c >> 6, cc0 = c & 63;
  float wreg[32], areg[32];
  #pragma unroll
  for (int d = 0; d < 32; d++){ wreg[d] = w2[d*CC + c]; areg[d] = a2[d*CC + c]; }
  float w0c = w0[c], a0c = a0[c];
  float w4a[4], a4a[4];
  #pragma unroll
  for (int g = 0; g < 4; g++){
    float wa = 0.f, aa = 0.f;
    #pragma unroll
    for (int d = 0; d < 32; d++){
      wa = fmaf(sth[g][d], wreg[d], wa);
      aa = fmaf(sal[g][d], areg[d], aa);
    }
    w4a[g] = __expf(-0.60653066f * sigm(w0c + wa));
    a4a[g] = sigm(a0c + aa);
  }
  size_t o = ((size_t)(bq*HH + h)*TG + tg)*64 + cc0;
  ((float4*)wP)[o] = make_float4(w4a[0],w4a[1],w4a[2],w4a[3]);
  ((float4*)aP)[o] = make_float4(a4a[0],a4a[1],a4a[2],a4a[3]);
}

// ---------------------------------------------------------------------------
// K3: BACKWARD vector scan — R5-measured geometry (256 blocks x 64 thr).
// R11: (1) vf-passthrough stores moved AFTER the prefetch loads — vmcnt
// counts loads AND stores in one counter, so stores issued first forced the
// load-consume waits to drain store retirement into the serial chain (R10:
// scan 52->70us).  Now stores are youngest per iteration.  (2) k,b computed
// in-flight from kgP/kkP/aP (+3 VALU/step) so the kP/bP round-trip (66MB)
// is deleted from k_wa.
//   out += v_s (k_s . g_s);  g_{s-1} = w_s*g_s - kk_s (b_s . g_s)
//   k = kg*(1+(a-1)k_a),  b = kk*a.
// ---------------------------------------------------------------------------
#define SCAN_STEP(wc,ac,gc,nc,pc,sc,vfc) do{ \
  float vj = fmaf((vfc)-(pc), (sc), (pc)); \
  float kc = (gc)*fmaf((ac)-1.f, kac, 1.f); \
  float bc = (nc)*(ac); \
  float rr[2]; rr[0]=kc*g; rr[1]=bc*g; \
  rowsum64_batch<2>(rr); \
  out = fmaf(rr[0], vj, out); \
  g = fmaf((wc), g, -((nc)*rr[1])); }while(0)

__global__ __launch_bounds__(64, 1) void k_scan(
  const float* __restrict__ wP, const float* __restrict__ aP,
  const float* __restrict__ kgP, const float* __restrict__ kkP,
  const float* __restrict__ vpP, const float* __restrict__ svP,
  const float* __restrict__ vfirst,
  const float* __restrict__ rrow, const float* __restrict__ grow,
  const float* __restrict__ r_k, const float* __restrict__ k_a,
  const float* __restrict__ ln_w, const float* __restrict__ ln_b,
  float* __restrict__ xo, float* __restrict__ vf_out)
{
  int blk = blockIdx.x; int bq = blk >> 3, h = blk & 7, b = bq >> 3;
  int lane = threadIdx.x & 63;

  // per-(bq,h)/(b,h) packed bases: TG*64 float4s each
  const float4* wp4 = (const float4*)wP  + ((size_t)(bq*HH + h))*TG*64 + lane;
  const float4* ap4 = (const float4*)aP  + ((size_t)(bq*HH + h))*TG*64 + lane;
  const float4* gp4 = (const float4*)kgP + ((size_t)(b*HH + h))*TG*64 + lane;
  const float4* np4 = (const float4*)kkP + ((size_t)(b*HH + h))*TG*64 + lane;
  const float4* pp4 = (const float4*)vpP + ((size_t)(b*HH + h))*TG*64 + lane;
  const float4* sp4 = (const float4*)svP + ((size_t)(b*HH + h))*TG*64 + lane;
  const float*  pvf = vfirst + (size_t)bq*TT*CC + h*NN + lane;
  float*        pvo = vf_out + (size_t)bq*TT*CC + h*NN + lane;

  float kac = k_a[h*NN + lane];
  float g   = rrow[(size_t)bq*CC + h*NN + lane];   // g_{T-1} = r
  float out = 0.f;

  constexpr int PD = 4;                // prefetch depth, in groups of 4 steps
  float4 fw[PD], fa[PD], fg[PD], fn[PD], fp[PD], fs[PD];
  float fv0[PD], fv1[PD], fv2[PD], fv3[PD];
  #pragma unroll
  for (int d = 0; d < PD; ++d){
    int gg = TG-1 - d; int go = gg*64;
    fw[d]=wp4[go]; fa[d]=ap4[go]; fg[d]=gp4[go]; fn[d]=np4[go];
    fp[d]=pp4[go]; fs[d]=sp4[go];
    const float* pv = pvf + (size_t)(4*gg)*CC;
    fv0[d]=pv[0]; fv1[d]=pv[CC]; fv2[d]=pv[2*CC]; fv3[d]=pv[3*CC];
  }

  #pragma unroll 1
  for (int gb = 0; gb < TG; gb += PD){
    #pragma unroll
    for (int sl = 0; sl < PD; ++sl){
      int gi = TG-1 - (gb + sl);       // current group (descending)
      // snapshot slot
      float4 w4=fw[sl], a4=fa[sl], g4=fg[sl], n4=fn[sl], p4=fp[sl], s4=fs[sl];
      float v3=fv3[sl], v2_=fv2[sl], v1_=fv1[sl], v0_=fv0[sl];
      // prefetch group gi-PD into slot sl (clamped; dup loads harmless)
      int gp = gi - PD; gp = gp < 0 ? 0 : gp; int go = gp*64;
      fw[sl]=wp4[go]; fa[sl]=ap4[go]; fg[sl]=gp4[go]; fn[sl]=np4[go];
      fp[sl]=pp4[go]; fs[sl]=sp4[go];
      { const float* pv = pvf + (size_t)(4*gp)*CC;
        fv0[sl]=pv[0]; fv1[sl]=pv[CC]; fv2[sl]=pv[2*CC]; fv3[sl]=pv[3*CC]; }
      // v_first passthrough: issued AFTER the prefetch loads so the stores
      // are the youngest vmem ops — load-consume vmcnt waits no longer
      // require store retirement (R10 regression mechanism).
      {
        float* po = pvo + (size_t)(4*gi)*CC;
        po[0] = v0_; po[CC] = v1_; po[2*CC] = v2_; po[3*CC] = v3;
      }
      __builtin_amdgcn_sched_barrier(0);   // pin loads/stores in this iteration
      // 4 steps, s = 4*gi+3 .. 4*gi+0
      SCAN_STEP(w4.w,a4.w,g4.w,n4.w,p4.w,s4.w,v3);
      SCAN_STEP(w4.z,a4.z,g4.z,n4.z,p4.z,s4.z,v2_);
      SCAN_STEP(w4.y,a4.y,g4.y,n4.y,p4.y,s4.y,v1_);
      SCAN_STEP(w4.x,a4.x,g4.x,n4.x,p4.x,s4.x,v0_);
    }
  }

  // epilogue: groupnorm over head + rk*v term + gate (per-lane channel)
  {
    float mean = wsum(out) * (1.f/NN);
    float dv = out - mean;
    float var = wsum(dv*dv) * (1.f/NN);
    float yn = dv * rsqrtf(var + 6.4e-4f);   // GN_EPS = 1e-5*64
    int c = h*NN + lane;
    float y2 = yn * ln_w[c] + ln_b[c];
    int goT = (TG-1)*64;
    float kgT = gp4[goT].w, aT = ap4[goT].w;
    float kl  = kgT * fmaf(aT - 1.f, kac, 1.f);   // k_final at t = T-1
    float rl  = rrow[(size_t)bq*CC + c];
    float rk  = wsum(rl*kl*r_k[c]);
    float vp_ = pp4[goT].w, sv_ = sp4[goT].w;
    float vf_ = pvf[(size_t)(TT-1)*CC];
    float v_i = fmaf(vf_ - vp_, sv_, vp_);   // v_{T-1}
    float res = (y2 + rk*v_i) * grow[(size_t)bq*CC + c];
    xo[bq*CC + c] = res;
  }
}

// ---------------------------------------------------------------------------
// K4: out[bq,co] = xo[bq,:] @ Wo[:,co]
// ---------------------------------------------------------------------------
__global__ __launch_bounds__(256) void k_out(
  const float* __restrict__ xo, const float* __restrict__ Wo,
  float* __restrict__ outp)
{
  int bq = blockIdx.y; int co0 = blockIdx.x*64;
  int tid = threadIdx.x, tx = tid & 63, ty = tid >> 6;
  __shared__ float row[CC];
  __shared__ float red[4][64];
  row[tid]     = xo[bq*CC + tid];
  row[tid+256] = xo[bq*CC + tid + 256];
  __syncthreads();
  float p = 0.f;
  for (int i = 0; i < 128; i++){
    int c = ty*128 + i;
    p = fmaf(row[c], Wo[(size_t)c*CC + co0 + tx], p);
  }
  red[ty][tx] = p;
  __syncthreads();
  if (ty == 0)
    outp[bq*CC + co0 + tx] = (red[0][tx]+red[1][tx])+(red[2][tx]+red[3][tx]);
}

// ---------------------------------------------------------------------------
extern "C" void kernel_launch(void* const* d_in, const int* in_sizes, int n_in,
                              void* d_out, int out_size, void* d_ws, size_t ws_size,
                              hipStream_t stream)
{
  const float* q   = (const float*)d_in[0];
  const float* kv  = (const float*)d_in[1];
  const float* vf  = (const float*)d_in[2];
  const float* x_r = (const float*)d_in[3];
  const float* x_w = (const float*)d_in[4];
  const float* x_k = (const float*)d_in[5];
  const float* x_v = (const float*)d_in[6];
  const float* x_a = (const float*)d_in[7];
  const float* x_g = (const float*)d_in[8];
  const float* w0  = (const float*)d_in[9];
  const float* w1  = (const float*)d_in[10];
  const float* w2  = (const float*)d_in[11];
  const float* a0  = (const float*)d_in[12];
  const float* a1  = (const float*)d_in[13];
  const float* a2  = (const float*)d_in[14];
  const float* v0  = (const float*)d_in[15];
  const float* v1  = (const float*)d_in[16];
  const float* v2  = (const float*)d_in[17];
  const float* g1  = (const float*)d_in[18];
  const float* g2  = (const float*)d_in[19];
  const float* k_k = (const float*)d_in[20];
  const float* k_a = (const float*)d_in[21];
  const float* r_k = (const float*)d_in[22];
  const float* Wr  = (const float*)d_in[23];
  const float* Wk  = (const float*)d_in[24];
  const float* Wv  = (const float*)d_in[25];
  const float* Wo  = (const float*)d_in[26];
  const float* lnw = (const float*)d_in[27];
  const float* lnb = (const float*)d_in[28];
  float* outp = (float*)d_out;
  float* ws = (float*)d_ws;

  // workspace layout (floats)
  float* xk  = ws + 0;         // 4*512*512
  float* xv  = ws + 1048576;
  float* kgP = ws + 2097152;   // k raw, packed [b][h][tg][c][4]
  float* vpP = ws + 3145728;   // v_pre, packed
  float* svP = ws + 4194304;   // sigmoid lerp factor, packed
  float* kkP = ws + 5242880;   // normalized kk, packed
  float* Pw  = ws + 6291456;   // 4*512*32
  float* Pa  = ws + 6356992;
  float* Qw  = ws + 6422528;   // 32*32
  float* Qa  = ws + 6423552;
  float* HV  = ws + 6424576;   // 4*512*32
  float* rr  = ws + 7473152;   // 32*512
  float* gr  = ws + 7489536;
  float* xo  = ws + 7505920;
  float* wP  = ws + 7522304;   // 32*512*512 decay, packed [bq][h][tg][c][4]
  float* aP  = ws + 15910912;  // a_sig, packed
  float* xrw = ws + 32688128;  // 32*512
  float* ghw = ws + 32704512;  // 32*96

  k_prep<<<32, 256, 0, stream>>>(q, kv, x_r, x_w, x_a, x_g, w1, a1, g1,
                                 Qw, Qa, ghw, xrw);
  k_rg<<<dim3(8, 32), 256, 0, stream>>>(xrw, ghw, Wr, g2, rr, gr);
  k_shift<<<1024, 256, 0, stream>>>(kv, x_k, x_v, xk, xv);
  gemm2<<<dim3(8, 32, 2), 256, 0, stream>>>(xk, Wk, kgP, xv, Wv, vpP);
  k_pgemm<<<dim3(32, 3), 256, 0, stream>>>(kv, xv, x_w, x_a, w1, a1, v1,
                                           Pw, Pa, HV);
  k_svn<<<NB*TG, 512, 0, stream>>>(HV, v2, v0, k_k, kgP, svP, kkP);
  k_wa<<<BQ*TG, 512, 0, stream>>>(Pw, Pa, Qw, Qa, w2, a2, w0, a0, wP, aP);
  k_scan<<<BQ*HH, 64, 0, stream>>>(wP, aP, kgP, kkP, vpP, svP, vf, rr, gr,
                                   r_k, k_a, lnw, lnb, xo, outp + BQ*CC);
  k_out<<<dim3(8, 32), 256, 0, stream>>>(xo, Wo, outp);
}

// Round 12
// 329.438 us; speedup vs baseline: 1.2504x; 1.0561x over previous
//
#include <hip/hip_runtime.h>
#include <cstdint>

// Problem constants
#define TT 512   // KVLEN
#define CC 512   // C
#define HH 8     // heads
#define NN 64    // head dim
#define BQ 32    // BATCH*QLEN
#define NB 4     // BATCH
#define TG 128   // TT/4 packed groups

__device__ __forceinline__ float sigm(float x){ return 1.f/(1.f+__expf(-x)); }

__device__ __forceinline__ float wsum(float x){
  #pragma unroll
  for (int o=32;o;o>>=1) x += __shfl_xor(x, o, 64);
  return x;
}

// ---------------------------------------------------------------------------
// Batched wave64 row-sum, VALU-only: DPP row_ror tree + permlane16/32 swap.
// ---------------------------------------------------------------------------
template<int NR>
__device__ __forceinline__ void rowsum64_batch(float* x){
  #pragma unroll
  for (int i=0;i<NR;i++)
    x[i] += __int_as_float(__builtin_amdgcn_mov_dpp(__float_as_int(x[i]), 0x121, 0xf, 0xf, true));
  #pragma unroll
  for (int i=0;i<NR;i++)
    x[i] += __int_as_float(__builtin_amdgcn_mov_dpp(__float_as_int(x[i]), 0x122, 0xf, 0xf, true));
  #pragma unroll
  for (int i=0;i<NR;i++)
    x[i] += __int_as_float(__builtin_amdgcn_mov_dpp(__float_as_int(x[i]), 0x124, 0xf, 0xf, true));
  #pragma unroll
  for (int i=0;i<NR;i++)
    x[i] += __int_as_float(__builtin_amdgcn_mov_dpp(__float_as_int(x[i]), 0x128, 0xf, 0xf, true));
  float y[NR];
  #pragma unroll
  for (int i=0;i<NR;i++) asm("v_mov_b32 %0, %1" : "=v"(y[i]) : "v"(x[i]));
  #pragma unroll
  for (int i=0;i<NR;i++) asm("v_permlane16_swap_b32 %0, %1" : "+v"(x[i]), "+v"(y[i]));
  #pragma unroll
  for (int i=0;i<NR;i++) x[i] += y[i];
  #pragma unroll
  for (int i=0;i<NR;i++) asm("v_mov_b32 %0, %1" : "=v"(y[i]) : "v"(x[i]));
  #pragma unroll
  for (int i=0;i<NR;i++) asm("v_permlane32_swap_b32 %0, %1" : "+v"(x[i]), "+v"(y[i]));
  #pragma unroll
  for (int i=0;i<NR;i++) x[i] += y[i];
}

// ---------------------------------------------------------------------------
// k_prep: per-bq small dots (32 blocks): Qw[bq,32], Qa[bq,32], gh[bq,96],
// and xr row -> workspace.
// ---------------------------------------------------------------------------
__global__ __launch_bounds__(256) void k_prep(
  const float* __restrict__ q, const float* __restrict__ kv,
  const float* __restrict__ x_r, const float* __restrict__ x_w,
  const float* __restrict__ x_a, const float* __restrict__ x_g,
  const float* __restrict__ w1, const float* __restrict__ a1,
  const float* __restrict__ g1,
  float* __restrict__ Qw, float* __restrict__ Qa,
  float* __restrict__ ghw, float* __restrict__ xrw)
{
  int bq = blockIdx.x, b = bq >> 3, tid = threadIdx.x;
  int wave = tid >> 6, lane = tid & 63;
  __shared__ float qxw[CC], qxa[CC], sxg[CC];
  for (int c = tid; c < CC; c += 256){
    float qv = q[bq*CC + c];
    float kl = kv[((size_t)b*TT + (TT-1))*CC + c];
    xrw[bq*CC + c] = kl + (qv - kl)*x_r[c];
    sxg[c] = kl + (qv - kl)*x_g[c];
    qxw[c] = qv*x_w[c];
    qxa[c] = qv*x_a[c];
  }
  __syncthreads();
  for (int dot = wave; dot < 160; dot += 4){
    const float* buf; const float* W; int ld, dd;
    if (dot < 32)      { buf = qxw; W = w1; ld = 32; dd = dot; }
    else if (dot < 64) { buf = qxa; W = a1; ld = 32; dd = dot-32; }
    else               { buf = sxg; W = g1; ld = 96; dd = dot-64; }
    float s = 0.f;
    #pragma unroll
    for (int m = 0; m < 8; m++){
      int c = m*64 + lane;
      s = fmaf(buf[c], W[c*ld + dd], s);
    }
    s = wsum(s);
    if (lane == 0){
      if (dot < 32)      Qw[bq*32 + dd] = s;
      else if (dot < 64) Qa[bq*32 + dd] = s;
      else               ghw[bq*96 + dd] = sigm(s);
    }
  }
}

// ---------------------------------------------------------------------------
// k_rg: rrow[bq,co] = xr[bq,:]@Wr[:,co], grow[bq,co] = gh[bq,:]@g2[:,co]
// ---------------------------------------------------------------------------
__global__ __launch_bounds__(256) void k_rg(
  const float* __restrict__ xrw, const float* __restrict__ ghw,
  const float* __restrict__ Wr, const float* __restrict__ g2,
  float* __restrict__ rrow, float* __restrict__ grow)
{
  int bq = blockIdx.y; int co0 = blockIdx.x*64;
  int tid = threadIdx.x, tx = tid & 63, ty = tid >> 6;
  __shared__ float sxr[CC];
  __shared__ float sgh[96];
  __shared__ float red[4][64];
  sxr[tid]     = xrw[bq*CC + tid];
  sxr[tid+256] = xrw[bq*CC + tid + 256];
  if (tid < 96) sgh[tid] = ghw[bq*96 + tid];
  __syncthreads();
  float p = 0.f;
  for (int i = 0; i < 128; i++){
    int c = ty*128 + i;
    p = fmaf(sxr[c], Wr[(size_t)c*CC + co0 + tx], p);
  }
  red[ty][tx] = p;
  float pg = 0.f;
  for (int d = ty*24; d < ty*24 + 24; d++)
    pg = fmaf(sgh[d], g2[(size_t)d*CC + co0 + tx], pg);
  __syncthreads();
  if (ty == 0)
    rrow[bq*CC + co0 + tx] = (red[0][tx]+red[1][tx])+(red[2][tx]+red[3][tx]);
  __syncthreads();
  red[ty][tx] = pg;
  __syncthreads();
  if (ty == 0)
    grow[bq*CC + co0 + tx] = (red[0][tx]+red[1][tx])+(red[2][tx]+red[3][tx]);
}

// ---------------------------------------------------------------------------
// k_shift: elementwise token-shift mix: xk, xv.  float4, coalesced.
// ---------------------------------------------------------------------------
__global__ __launch_bounds__(256) void k_shift(
  const float* __restrict__ kv, const float* __restrict__ x_k,
  const float* __restrict__ x_v,
  float* __restrict__ xk, float* __restrict__ xv)
{
  int g = blockIdx.x*256 + threadIdx.x;      // float4 index, [0, 262144)
  int bt = g >> 7, t = bt & (TT-1), c4 = g & 127;
  const float4* kv4 = (const float4*)kv;
  float4 cur = kv4[g];
  float4 sh  = t ? kv4[g-128] : make_float4(0.f,0.f,0.f,0.f);
  float4 kc  = ((const float4*)x_k)[c4];
  float4 vc  = ((const float4*)x_v)[c4];
  float4 ok, ov;
  ok.x = cur.x + (sh.x-cur.x)*kc.x; ov.x = cur.x + (sh.x-cur.x)*vc.x;
  ok.y = cur.y + (sh.y-cur.y)*kc.y; ov.y = cur.y + (sh.y-cur.y)*vc.y;
  ok.z = cur.z + (sh.z-cur.z)*kc.z; ov.z = cur.z + (sh.z-cur.z)*vc.z;
  ok.w = cur.w + (sh.w-cur.w)*kc.w; ov.w = cur.w + (sh.w-cur.w)*vc.w;
  ((float4*)xk)[g] = ok;
  ((float4*)xv)[g] = ov;
}

// ---------------------------------------------------------------------------
// k_mm: FUSED gemm2 + k_pgemm in one 608-block dispatch (R12).
// Blocks 0..95: the three [2048x512]@[512x32] products (latency-bound,
// placed FIRST so they start earliest and hide under the gemm blocks).
// Blocks 96..607: two [2048x512]@[512x512] (z = (bid-96)>>8), packed stores.
// Rationale: standalone k_pgemm (96 blocks) ran ~95% stall alone in-stream
// (R8); co-residency with 512 compute blocks hides it.
// ---------------------------------------------------------------------------
__global__ __launch_bounds__(256) void k_mm(
  const float* __restrict__ xk, const float* __restrict__ Wk,
  float* __restrict__ kgP,
  const float* __restrict__ xv, const float* __restrict__ Wv,
  float* __restrict__ vpP,
  const float* __restrict__ kv,
  const float* __restrict__ x_w, const float* __restrict__ x_a,
  const float* __restrict__ w1, const float* __restrict__ a1,
  const float* __restrict__ v1,
  float* __restrict__ Pw, float* __restrict__ Pa, float* __restrict__ HV)
{
  __shared__ float As[32][68];
  __shared__ float Bs[32][64];
  __shared__ float scl[CC];
  int bid = blockIdx.x;
  int tid = threadIdx.x;

  if (bid < 96){
    // ----- pgemm part -----
    int mat = bid / 32;
    int r0 = (bid % 32) * 64;
    const float* A = (mat == 2) ? xv : kv;
    const float* B = (mat == 0) ? w1 : (mat == 1) ? a1 : v1;
    float* O       = (mat == 0) ? Pw : (mat == 1) ? Pa : HV;
    for (int c = tid; c < CC; c += 256)
      scl[c] = (mat == 0) ? (1.f - x_w[c]) : (mat == 1) ? (1.f - x_a[c]) : 1.f;
    __syncthreads();
    int tx = tid & 31, ty = tid >> 5;
    float acc[8];
    #pragma unroll
    for (int i = 0; i < 8; i++) acc[i] = 0.f;
    for (int k0 = 0; k0 < 512; k0 += 32){
      #pragma unroll
      for (int p = 0; p < 8; p++){
        int e = tid + p*256;
        int kk2 = e & 31, r = e >> 5;
        As[kk2][r] = A[(size_t)(r0+r)*512 + k0 + kk2] * scl[k0 + kk2];
      }
      #pragma unroll
      for (int p = 0; p < 4; p++){
        int e = tid + p*256;
        int n = e & 31, kk2 = e >> 5;
        Bs[kk2][n] = B[(size_t)(k0+kk2)*32 + n];
      }
      __syncthreads();
      #pragma unroll
      for (int kk2 = 0; kk2 < 32; kk2++){
        float bb = Bs[kk2][tx];
        #pragma unroll
        for (int i = 0; i < 8; i++)
          acc[i] = fmaf(As[kk2][ty*8 + i], bb, acc[i]);
      }
      __syncthreads();
    }
    #pragma unroll
    for (int i = 0; i < 8; i++)
      O[(size_t)(r0 + ty*8 + i)*32 + tx] = acc[i];
  } else {
    // ----- gemm part -----
    int gb = bid - 96;
    int z = gb >> 8; int tile = gb & 255;
    const float* A = z ? xv : xk;
    const float* W = z ? Wv : Wk;
    int tx = tid & 15, ty = tid >> 4;
    int m0 = (tile >> 3)*64, n0 = (tile & 7)*64;
    float acc[4][4];
    #pragma unroll
    for (int i=0;i<4;i++)
      #pragma unroll
      for (int j=0;j<4;j++) acc[i][j]=0.f;

    for (int k0 = 0; k0 < 512; k0 += 32){
      #pragma unroll
      for (int i = 0; i < 8; i++){
        int e = tid + i*256;
        int kk = e & 31, m = e >> 5;
        As[kk][m] = A[(size_t)(m0+m)*512 + k0 + kk];
      }
      #pragma unroll
      for (int i = 0; i < 8; i++){
        int e = tid + i*256;
        int n = e & 63, kk = e >> 6;
        Bs[kk][n] = W[(size_t)(k0+kk)*512 + n0 + n];
      }
      __syncthreads();
      #pragma unroll
      for (int kk = 0; kk < 32; kk++){
        float a4[4], b4[4];
        #pragma unroll
        for (int i=0;i<4;i++) a4[i] = As[kk][ty*4+i];
        #pragma unroll
        for (int j=0;j<4;j++) b4[j] = Bs[kk][tx*4+j];
        #pragma unroll
        for (int i=0;i<4;i++)
          #pragma unroll
          for (int j=0;j<4;j++) acc[i][j] += a4[i]*b4[j];
      }
      __syncthreads();
    }
    // packed store: rows m..m+3 are 4 consecutive t (u=0..3)
    int m = m0 + ty*4;
    int b = m >> 9, t = m & (TT-1), tg = t >> 2;
    int h = n0 >> 6;
    float* dstB = z ? vpP : kgP;
    float4* dst = (float4*)dstB + ((size_t)(b*HH + h)*TG + tg)*64 + tx*4;
    #pragma unroll
    for (int j=0;j<4;j++)
      dst[j] = make_float4(acc[0][j],acc[1][j],acc[2][j],acc[3][j]);
  }
}

// ---------------------------------------------------------------------------
// k_swa: FUSED k_svn + k_wa in one 4608-block dispatch (R12); both 512-thr,
// mutually independent.  Blocks 0..511: svn (kk-normalize + sv, packed).
// Blocks 512..4607: wa (decay w + a_sig, packed).
// ---------------------------------------------------------------------------
__global__ __launch_bounds__(512) void k_swa(
  const float* __restrict__ HV, const float* __restrict__ v2,
  const float* __restrict__ v0, const float* __restrict__ k_k,
  const float* __restrict__ kgP,
  float* __restrict__ svP, float* __restrict__ kkP,
  const float* __restrict__ Pw, const float* __restrict__ Pa,
  const float* __restrict__ Qw, const float* __restrict__ Qa,
  const float* __restrict__ w2, const float* __restrict__ a2,
  const float* __restrict__ w0, const float* __restrict__ a0,
  float* __restrict__ wP, float* __restrict__ aP)
{
  int bid = blockIdx.x;
  int tid = threadIdx.x;
  if (bid < NB*TG){
    // ----- svn part -----
    int b = bid >> 7, tg = bid & (TG-1);
    __shared__ float hv[4][32];
    if (tid < 128){
      int u = tid >> 5, d = tid & 31;
      hv[u][d] = HV[((size_t)(b*TT + tg*4 + u))*32 + d];
    }
    __syncthreads();
    int c = tid, h = c >> 6, cc0 = c & 63;
    size_t o = ((size_t)(b*HH + h)*TG + tg)*64 + cc0;
    float4 kg4 = ((const float4*)kgP)[o];
    float kkc = k_k[c];
    float q0 = kg4.x*kkc, q1 = kg4.y*kkc, q2 = kg4.z*kkc, q3 = kg4.w*kkc;
    float ss[4] = {q0*q0, q1*q1, q2*q2, q3*q3};
    rowsum64_batch<4>(ss);            // per-wave = per-head sum
    float4 kkq;
    kkq.x = q0 / fmaxf(sqrtf(ss[0]), 1e-12f);
    kkq.y = q1 / fmaxf(sqrtf(ss[1]), 1e-12f);
    kkq.z = q2 / fmaxf(sqrtf(ss[2]), 1e-12f);
    kkq.w = q3 / fmaxf(sqrtf(ss[3]), 1e-12f);
    ((float4*)kkP)[o] = kkq;
    float v0c = v0[c];
    float s0 = v0c, s1 = v0c, s2 = v0c, s3 = v0c;
    #pragma unroll
    for (int d = 0; d < 32; d++){
      float vc = v2[d*CC + c];
      s0 = fmaf(hv[0][d], vc, s0);
      s1 = fmaf(hv[1][d], vc, s1);
      s2 = fmaf(hv[2][d], vc, s2);
      s3 = fmaf(hv[3][d], vc, s3);
    }
    ((float4*)svP)[o] = make_float4(sigm(s0), sigm(s1), sigm(s2), sigm(s3));
  } else {
    // ----- wa part -----
    int blk = bid - NB*TG;             // bq*TG + tg
    int bq = blk >> 7, tg = blk & (TG-1), t0 = tg*4, b = bq >> 3;
    __shared__ float sth[4][32], sal[4][32];
    if (tid < 256){
      int g = (tid >> 5) & 3, d = tid & 31;
      int pidx = ((b << 9) | (t0 + g))*32 + d;
      if (tid < 128) sth[g][d] = tanhf(Pw[pidx] + Qw[bq*32 + d]);
      else           sal[g][d] = Pa[pidx] + Qa[bq*32 + d];
    }
    __syncthreads();
    int c = tid, h = c >> 6, cc0 = c & 63;
    float wreg[32], areg[32];
    #pragma unroll
    for (int d = 0; d < 32; d++){ wreg[d] = w2[d*CC + c]; areg[d] = a2[d*CC + c]; }
    float w0c = w0[c], a0c = a0[c];
    float w4a[4], a4a[4];
    #pragma unroll
    for (int g = 0; g < 4; g++){
      float wa = 0.f, aa = 0.f;
      #pragma unroll
      for (int d = 0; d < 32; d++){
        wa = fmaf(sth[g][d], wreg[d], wa);
        aa = fmaf(sal[g][d], areg[d], aa);
      }
      w4a[g] = __expf(-0.60653066f * sigm(w0c + wa));
      a4a[g] = sigm(a0c + aa);
    }
    size_t o = ((size_t)(bq*HH + h)*TG + tg)*64 + cc0;
    ((float4*)wP)[o] = make_float4(w4a[0],w4a[1],w4a[2],w4a[3]);
    ((float4*)aP)[o] = make_float4(a4a[0],a4a[1],a4a[2],a4a[3]);
  }
}

// ---------------------------------------------------------------------------
// K3: BACKWARD vector scan — R11 structure (63us measured): R5 geometry,
// vf-passthrough stores youngest per iteration, k/b in-flight.
//   out += v_s (k_s . g_s);  g_{s-1} = w_s*g_s - kk_s (b_s . g_s)
//   k = kg*(1+(a-1)k_a),  b = kk*a.
// ---------------------------------------------------------------------------
#define SCAN_STEP(wc,ac,gc,nc,pc,sc,vfc) do{ \
  float vj = fmaf((vfc)-(pc), (sc), (pc)); \
  float kc = (gc)*fmaf((ac)-1.f, kac, 1.f); \
  float bc = (nc)*(ac); \
  float rr[2]; rr[0]=kc*g; rr[1]=bc*g; \
  rowsum64_batch<2>(rr); \
  out = fmaf(rr[0], vj, out); \
  g = fmaf((wc), g, -((nc)*rr[1])); }while(0)

__global__ __launch_bounds__(64, 1) void k_scan(
  const float* __restrict__ wP, const float* __restrict__ aP,
  const float* __restrict__ kgP, const float* __restrict__ kkP,
  const float* __restrict__ vpP, const float* __restrict__ svP,
  const float* __restrict__ vfirst,
  const float* __restrict__ rrow, const float* __restrict__ grow,
  const float* __restrict__ r_k, const float* __restrict__ k_a,
  const float* __restrict__ ln_w, const float* __restrict__ ln_b,
  float* __restrict__ xo, float* __restrict__ vf_out)
{
  int blk = blockIdx.x; int bq = blk >> 3, h = blk & 7, b = bq >> 3;
  int lane = threadIdx.x & 63;

  // per-(bq,h)/(b,h) packed bases: TG*64 float4s each
  const float4* wp4 = (const float4*)wP  + ((size_t)(bq*HH + h))*TG*64 + lane;
  const float4* ap4 = (const float4*)aP  + ((size_t)(bq*HH + h))*TG*64 + lane;
  const float4* gp4 = (const float4*)kgP + ((size_t)(b*HH + h))*TG*64 + lane;
  const float4* np4 = (const float4*)kkP + ((size_t)(b*HH + h))*TG*64 + lane;
  const float4* pp4 = (const float4*)vpP + ((size_t)(b*HH + h))*TG*64 + lane;
  const float4* sp4 = (const float4*)svP + ((size_t)(b*HH + h))*TG*64 + lane;
  const float*  pvf = vfirst + (size_t)bq*TT*CC + h*NN + lane;
  float*        pvo = vf_out + (size_t)bq*TT*CC + h*NN + lane;

  float kac = k_a[h*NN + lane];
  float g   = rrow[(size_t)bq*CC + h*NN + lane];   // g_{T-1} = r
  float out = 0.f;

  constexpr int PD = 4;                // prefetch depth, in groups of 4 steps
  float4 fw[PD], fa[PD], fg[PD], fn[PD], fp[PD], fs[PD];
  float fv0[PD], fv1[PD], fv2[PD], fv3[PD];
  #pragma unroll
  for (int d = 0; d < PD; ++d){
    int gg = TG-1 - d; int go = gg*64;
    fw[d]=wp4[go]; fa[d]=ap4[go]; fg[d]=gp4[go]; fn[d]=np4[go];
    fp[d]=pp4[go]; fs[d]=sp4[go];
    const float* pv = pvf + (size_t)(4*gg)*CC;
    fv0[d]=pv[0]; fv1[d]=pv[CC]; fv2[d]=pv[2*CC]; fv3[d]=pv[3*CC];
  }

  #pragma unroll 1
  for (int gb = 0; gb < TG; gb += PD){
    #pragma unroll
    for (int sl = 0; sl < PD; ++sl){
      int gi = TG-1 - (gb + sl);       // current group (descending)
      // snapshot slot
      float4 w4=fw[sl], a4=fa[sl], g4=fg[sl], n4=fn[sl], p4=fp[sl], s4=fs[sl];
      float v3=fv3[sl], v2_=fv2[sl], v1_=fv1[sl], v0_=fv0[sl];
      // prefetch group gi-PD into slot sl (clamped; dup loads harmless)
      int gp = gi - PD; gp = gp < 0 ? 0 : gp; int go = gp*64;
      fw[sl]=wp4[go]; fa[sl]=ap4[go]; fg[sl]=gp4[go]; fn[sl]=np4[go];
      fp[sl]=pp4[go]; fs[sl]=sp4[go];
      { const float* pv = pvf + (size_t)(4*gp)*CC;
        fv0[sl]=pv[0]; fv1[sl]=pv[CC]; fv2[sl]=pv[2*CC]; fv3[sl]=pv[3*CC]; }
      // v_first passthrough: issued AFTER the prefetch loads so the stores
      // are the youngest vmem ops — load-consume vmcnt waits no longer
      // require store retirement (R10 regression mechanism).
      {
        float* po = pvo + (size_t)(4*gi)*CC;
        po[0] = v0_; po[CC] = v1_; po[2*CC] = v2_; po[3*CC] = v3;
      }
      __builtin_amdgcn_sched_barrier(0);   // pin loads/stores in this iteration
      // 4 steps, s = 4*gi+3 .. 4*gi+0
      SCAN_STEP(w4.w,a4.w,g4.w,n4.w,p4.w,s4.w,v3);
      SCAN_STEP(w4.z,a4.z,g4.z,n4.z,p4.z,s4.z,v2_);
      SCAN_STEP(w4.y,a4.y,g4.y,n4.y,p4.y,s4.y,v1_);
      SCAN_STEP(w4.x,a4.x,g4.x,n4.x,p4.x,s4.x,v0_);
    }
  }

  // epilogue: groupnorm over head + rk*v term + gate (per-lane channel)
  {
    float mean = wsum(out) * (1.f/NN);
    float dv = out - mean;
    float var = wsum(dv*dv) * (1.f/NN);
    float yn = dv * rsqrtf(var + 6.4e-4f);   // GN_EPS = 1e-5*64
    int c = h*NN + lane;
    float y2 = yn * ln_w[c] + ln_b[c];
    int goT = (TG-1)*64;
    float kgT = gp4[goT].w, aT = ap4[goT].w;
    float kl  = kgT * fmaf(aT - 1.f, kac, 1.f);   // k_final at t = T-1
    float rl  = rrow[(size_t)bq*CC + c];
    float rk  = wsum(rl*kl*r_k[c]);
    float vp_ = pp4[goT].w, sv_ = sp4[goT].w;
    float vf_ = pvf[(size_t)(TT-1)*CC];
    float v_i = fmaf(vf_ - vp_, sv_, vp_);   // v_{T-1}
    float res = (y2 + rk*v_i) * grow[(size_t)bq*CC + c];
    xo[bq*CC + c] = res;
  }
}

// ---------------------------------------------------------------------------
// K4: out[bq,co] = xo[bq,:] @ Wo[:,co]
// ---------------------------------------------------------------------------
__global__ __launch_bounds__(256) void k_out(
  const float* __restrict__ xo, const float* __restrict__ Wo,
  float* __restrict__ outp)
{
  int bq = blockIdx.y; int co0 = blockIdx.x*64;
  int tid = threadIdx.x, tx = tid & 63, ty = tid >> 6;
  __shared__ float row[CC];
  __shared__ float red[4][64];
  row[tid]     = xo[bq*CC + tid];
  row[tid+256] = xo[bq*CC + tid + 256];
  __syncthreads();
  float p = 0.f;
  for (int i = 0; i < 128; i++){
    int c = ty*128 + i;
    p = fmaf(row[c], Wo[(size_t)c*CC + co0 + tx], p);
  }
  red[ty][tx] = p;
  __syncthreads();
  if (ty == 0)
    outp[bq*CC + co0 + tx] = (red[0][tx]+red[1][tx])+(red[2][tx]+red[3][tx]);
}

// ---------------------------------------------------------------------------
extern "C" void kernel_launch(void* const* d_in, const int* in_sizes, int n_in,
                              void* d_out, int out_size, void* d_ws, size_t ws_size,
                              hipStream_t stream)
{
  const float* q   = (const float*)d_in[0];
  const float* kv  = (const float*)d_in[1];
  const float* vf  = (const float*)d_in[2];
  const float* x_r = (const float*)d_in[3];
  const float* x_w = (const float*)d_in[4];
  const float* x_k = (const float*)d_in[5];
  const float* x_v = (const float*)d_in[6];
  const float* x_a = (const float*)d_in[7];
  const float* x_g = (const float*)d_in[8];
  const float* w0  = (const float*)d_in[9];
  const float* w1  = (const float*)d_in[10];
  const float* w2  = (const float*)d_in[11];
  const float* a0  = (const float*)d_in[12];
  const float* a1  = (const float*)d_in[13];
  const float* a2  = (const float*)d_in[14];
  const float* v0  = (const float*)d_in[15];
  const float* v1  = (const float*)d_in[16];
  const float* v2  = (const float*)d_in[17];
  const float* g1  = (const float*)d_in[18];
  const float* g2  = (const float*)d_in[19];
  const float* k_k = (const float*)d_in[20];
  const float* k_a = (const float*)d_in[21];
  const float* r_k = (const float*)d_in[22];
  const float* Wr  = (const float*)d_in[23];
  const float* Wk  = (const float*)d_in[24];
  const float* Wv  = (const float*)d_in[25];
  const float* Wo  = (const float*)d_in[26];
  const float* lnw = (const float*)d_in[27];
  const float* lnb = (const float*)d_in[28];
  float* outp = (float*)d_out;
  float* ws = (float*)d_ws;

  // workspace layout (floats)
  float* xk  = ws + 0;         // 4*512*512
  float* xv  = ws + 1048576;
  float* kgP = ws + 2097152;   // k raw, packed [b][h][tg][c][4]
  float* vpP = ws + 3145728;   // v_pre, packed
  float* svP = ws + 4194304;   // sigmoid lerp factor, packed
  float* kkP = ws + 5242880;   // normalized kk, packed
  float* Pw  = ws + 6291456;   // 4*512*32
  float* Pa  = ws + 6356992;
  float* Qw  = ws + 6422528;   // 32*32
  float* Qa  = ws + 6423552;
  float* HV  = ws + 6424576;   // 4*512*32
  float* rr  = ws + 7473152;   // 32*512
  float* gr  = ws + 7489536;
  float* xo  = ws + 7505920;
  float* wP  = ws + 7522304;   // 32*512*512 decay, packed [bq][h][tg][c][4]
  float* aP  = ws + 15910912;  // a_sig, packed
  float* xrw = ws + 32688128;  // 32*512
  float* ghw = ws + 32704512;  // 32*96

  k_prep<<<32, 256, 0, stream>>>(q, kv, x_r, x_w, x_a, x_g, w1, a1, g1,
                                 Qw, Qa, ghw, xrw);
  k_rg<<<dim3(8, 32), 256, 0, stream>>>(xrw, ghw, Wr, g2, rr, gr);
  k_shift<<<1024, 256, 0, stream>>>(kv, x_k, x_v, xk, xv);
  k_mm<<<608, 256, 0, stream>>>(xk, Wk, kgP, xv, Wv, vpP, kv,
                                x_w, x_a, w1, a1, v1, Pw, Pa, HV);
  k_swa<<<NB*TG + BQ*TG, 512, 0, stream>>>(HV, v2, v0, k_k, kgP, svP, kkP,
                                           Pw, Pa, Qw, Qa, w2, a2, w0, a0,
                                           wP, aP);
  k_scan<<<BQ*HH, 64, 0, stream>>>(wP, aP, kgP, kkP, vpP, svP, vf, rr, gr,
                                   r_k, k_a, lnw, lnb, xo, outp + BQ*CC);
  k_out<<<dim3(8, 32), 256, 0, stream>>>(xo, Wo, outp);
}